// Round 1
// 661.912 us; speedup vs baseline: 1.2187x; 1.2187x over previous
//
#include <hip/hip_runtime.h>
#include <hip/hip_fp16.h>

#define N_DST 100000
#define DIN 128
#define HDIM 64
#define RREL 3
#define NE 1000000

#define NBKT_REL 196              // ceil(100000/512) buckets per relation
#define NBKT (RREL * NBKT_REL)    // 588 total buckets
#define NSEG (RREL * N_DST)       // 300000 segments
#define EDGE_CHUNK 16384
#define NBLK_BIN ((RREL * NE + EDGE_CHUNK - 1) / EDGE_CHUNK)  // 184

// ---------------- GEMM: h = A @ W + b  (4 matrices: dst + 3 relations) ----------------
// Epilogue fused: computes attention logits el/er via cross-lane reduce (k_logits
// eliminated) and stores h for relations as fp16 (halves aggregate gather bytes).
// dst matrix (mat==0) only needs er[0..2]; its h rows are never materialized.
__global__ __launch_bounds__(256) void k_gemm(
    const float* __restrict__ dst_feat, const float* __restrict__ neigh,
    const float* __restrict__ Wt, const float* __restrict__ bt,
    const float* __restrict__ attn_l, const float* __restrict__ attn_r,
    __half* __restrict__ h16, float* __restrict__ el, float* __restrict__ er) {
  const int RB = (N_DST + 63) / 64;  // 1563 row-blocks per matrix
  int mat = blockIdx.x / RB;
  int row0 = (blockIdx.x % RB) * 64;
  const float* A = (mat == 0) ? dst_feat : (neigh + (size_t)(mat - 1) * N_DST * DIN);
  const float* W = Wt + (size_t)mat * DIN * HDIM;
  const float* b = bt + mat * HDIM;

  __shared__ float Wl[DIN * HDIM];  // 32 KB
  __shared__ float Al[64 * 36];     // 64 rows x 32-k chunk, stride 36 (bank-safe)

  int tid = threadIdx.x;
  for (int i = tid * 4; i < DIN * HDIM; i += 1024)
    *(float4*)(Wl + i) = *(const float4*)(W + i);

  int tc = tid & 15;  // cols 4*tc .. 4*tc+3
  int tr = tid >> 4;  // rows 4*tr .. 4*tr+3
  float acc[4][4] = {};

  for (int k0 = 0; k0 < DIN; k0 += 32) {
    __syncthreads();
    for (int s = tid; s < 512; s += 256) {
      int r = s >> 3;
      int kq = (s & 7) << 2;
      int gr = row0 + r;
      if (gr >= N_DST) gr = N_DST - 1;  // clamp (tail block)
      *(float4*)(Al + r * 36 + kq) = *(const float4*)(A + (size_t)gr * DIN + k0 + kq);
    }
    __syncthreads();
#pragma unroll
    for (int kk = 0; kk < 32; kk += 4) {
      float4 av[4], wv[4];
#pragma unroll
      for (int i = 0; i < 4; i++) av[i] = *(float4*)(Al + (4 * tr + i) * 36 + kk);
#pragma unroll
      for (int j = 0; j < 4; j++) wv[j] = *(float4*)(Wl + (k0 + kk + j) * HDIM + 4 * tc);
#pragma unroll
      for (int i = 0; i < 4; i++) {
        const float* ap = (const float*)&av[i];
#pragma unroll
        for (int j = 0; j < 4; j++) {
          const float* wp = (const float*)&wv[j];
          float a = ap[j];
#pragma unroll
          for (int c = 0; c < 4; c++) acc[i][c] += a * wp[c];
        }
      }
    }
  }

  // add bias into accumulators (reference logits use h including bias)
  float bv[4];
#pragma unroll
  for (int c = 0; c < 4; c++) bv[c] = b[4 * tc + c];
#pragma unroll
  for (int i = 0; i < 4; i++)
#pragma unroll
    for (int c = 0; c < 4; c++) acc[i][c] += bv[c];

  if (mat == 0) {
    // er[r][n] = h_dst[n] . attn_r[r]  for all 3 relations
#pragma unroll
    for (int r = 0; r < RREL; r++) {
      float p[4];
#pragma unroll
      for (int i = 0; i < 4; i++) {
        p[i] = 0.f;
#pragma unroll
        for (int c = 0; c < 4; c++) p[i] += acc[i][c] * attn_r[r * HDIM + 4 * tc + c];
      }
#pragma unroll
      for (int o = 1; o < 16; o <<= 1) {
#pragma unroll
        for (int i = 0; i < 4; i++) p[i] += __shfl_xor(p[i], o);
      }
      if (tc == 0) {
#pragma unroll
        for (int i = 0; i < 4; i++) {
          int gr = row0 + 4 * tr + i;
          if (gr < N_DST) er[r * N_DST + gr] = p[i];
        }
      }
    }
  } else {
    int r = mat - 1;
    // el[r][n] = h_src[r][n] . attn_l[r]
    float p[4];
#pragma unroll
    for (int i = 0; i < 4; i++) {
      p[i] = 0.f;
#pragma unroll
      for (int c = 0; c < 4; c++) p[i] += acc[i][c] * attn_l[r * HDIM + 4 * tc + c];
    }
#pragma unroll
    for (int o = 1; o < 16; o <<= 1) {
#pragma unroll
      for (int i = 0; i < 4; i++) p[i] += __shfl_xor(p[i], o);
    }
    if (tc == 0) {
#pragma unroll
      for (int i = 0; i < 4; i++) {
        int gr = row0 + 4 * tr + i;
        if (gr < N_DST) el[r * N_DST + gr] = p[i];
      }
    }
    // fp16 h store (8B per row per thread)
#pragma unroll
    for (int i = 0; i < 4; i++) {
      int gr = row0 + 4 * tr + i;
      if (gr < N_DST) {
        union {
          __half2 h2[2];
          float2 f2;
        } u;
        u.h2[0] = __floats2half2_rn(acc[i][0], acc[i][1]);
        u.h2[1] = __floats2half2_rn(acc[i][2], acc[i][3]);
        *(float2*)(h16 + ((size_t)r * N_DST + gr) * HDIM + 4 * tc) = u.f2;
      }
    }
  }
}

// ---------------- CSR build: counting-sort partition, zero global atomics ----------------
// Buckets: (relation, dst>>9) -> 588 buckets of 512 dst nodes; bucket order == segment order.

// 1) per-chunk histogram -> hist[bucket][block] (bucket-major)
__global__ __launch_bounds__(256) void k_hist(const int* __restrict__ dst_idx,
                                              int* __restrict__ hist) {
  __shared__ int h[NBKT];
  int tid = threadIdx.x;
  int blk = blockIdx.x;
  for (int i = tid; i < NBKT; i += 256) h[i] = 0;
  __syncthreads();
  int e0 = blk * EDGE_CHUNK;
  int e1 = min(e0 + EDGE_CHUNK, RREL * NE);
  for (int idx = e0 + tid; idx < e1; idx += 256) {
    int r = idx / NE;
    int d = dst_idx[idx];
    atomicAdd(&h[r * NBKT_REL + (d >> 9)], 1);
  }
  __syncthreads();
  for (int i = tid; i < NBKT; i += 256)
    hist[(size_t)i * NBLK_BIN + blk] = h[i];
}

// 2) per-bucket exclusive scan across blocks; bucket totals out
__global__ __launch_bounds__(256) void k_colscan(int* __restrict__ hist,
                                                 int* __restrict__ bcounts) {
  __shared__ int sm[256];
  int b = blockIdx.x;
  int tid = threadIdx.x;
  int v = (tid < NBLK_BIN) ? hist[(size_t)b * NBLK_BIN + tid] : 0;
  sm[tid] = v;
  __syncthreads();
  for (int off = 1; off < 256; off <<= 1) {
    int t = (tid >= off) ? sm[tid - off] : 0;
    __syncthreads();
    sm[tid] += t;
    __syncthreads();
  }
  if (tid < NBLK_BIN) hist[(size_t)b * NBLK_BIN + tid] = sm[tid] - v;  // exclusive
  if (tid == 255) bcounts[b] = sm[255];
}

// 3) scan 588 bucket totals -> bucket_base[589]; offsets[NSEG]=3M
__global__ __launch_bounds__(256) void k_bscan(const int* __restrict__ bcounts,
                                               int* __restrict__ bucket_base,
                                               int* __restrict__ offsets) {
  __shared__ int sm[256];
  int tid = threadIdx.x;
  int base = tid * 3;
  int c[3];
#pragma unroll
  for (int k = 0; k < 3; k++) c[k] = (base + k < NBKT) ? bcounts[base + k] : 0;
  int tsum = c[0] + c[1] + c[2];
  sm[tid] = tsum;
  __syncthreads();
  for (int off = 1; off < 256; off <<= 1) {
    int v = (tid >= off) ? sm[tid - off] : 0;
    __syncthreads();
    sm[tid] += v;
    __syncthreads();
  }
  int run = sm[tid] - tsum;
#pragma unroll
  for (int k = 0; k < 3; k++) {
    if (base + k < NBKT) bucket_base[base + k] = run;
    run += c[k];
  }
  if (tid == 255) bucket_base[NBKT] = sm[255];  // = RREL*NE
  if (tid == 0) offsets[NSEG] = RREL * NE;
}

// 4) place edges: per-block LDS cursors seeded from scanned bases; LDS atomics only.
//    Packed word (localdst<<17 | src); src < 2^17, localdst < 2^9.
__global__ __launch_bounds__(256) void k_place(const int* __restrict__ src_idx,
                                               const int* __restrict__ dst_idx,
                                               const int* __restrict__ hist,
                                               const int* __restrict__ bucket_base,
                                               unsigned* __restrict__ tmp) {
  __shared__ int cur[NBKT];
  int tid = threadIdx.x;
  int blk = blockIdx.x;
  for (int i = tid; i < NBKT; i += 256)
    cur[i] = bucket_base[i] + hist[(size_t)i * NBLK_BIN + blk];
  __syncthreads();
  int e0 = blk * EDGE_CHUNK;
  int e1 = min(e0 + EDGE_CHUNK, RREL * NE);
  for (int idx = e0 + tid; idx < e1; idx += 256) {
    int r = idx / NE;
    int d = dst_idx[idx];
    int s = src_idx[idx];
    int bucket = r * NBKT_REL + (d >> 9);
    int pos = atomicAdd(&cur[bucket], 1);
    tmp[pos] = ((unsigned)(d & 511) << 17) | (unsigned)s;
  }
}

// 5) per-bucket: LDS histogram of 512 local segments + block scan -> per-segment
//    offsets + final scatter (random writes confined to ~20 KB -> L2-combined).
__global__ __launch_bounds__(256) void k_bucket_csr(
    const int* __restrict__ bucket_base, const unsigned* __restrict__ tmp,
    int* __restrict__ src_sorted, int* __restrict__ offsets) {
  __shared__ int cnt[512];
  __shared__ int base_l[512];
  __shared__ int sm[256];
  int b = blockIdx.x;
  int r = b / NBKT_REL;
  int brel = b - r * NBKT_REL;
  int gbase = bucket_base[b];
  int gend = bucket_base[b + 1];
  int tid = threadIdx.x;
  cnt[tid] = 0;
  cnt[tid + 256] = 0;
  __syncthreads();
  for (int e = gbase + tid; e < gend; e += 256)
    atomicAdd(&cnt[tmp[e] >> 17], 1);
  __syncthreads();
  int c0 = cnt[2 * tid], c1 = cnt[2 * tid + 1];
  int tsum = c0 + c1;
  sm[tid] = tsum;
  __syncthreads();
  for (int off = 1; off < 256; off <<= 1) {
    int v = (tid >= off) ? sm[tid - off] : 0;
    __syncthreads();
    sm[tid] += v;
    __syncthreads();
  }
  int run = sm[tid] - tsum;
  base_l[2 * tid] = run;
  base_l[2 * tid + 1] = run + c0;
  __syncthreads();
  for (int s = tid; s < 512; s += 256) {
    int dst = (brel << 9) + s;
    if (dst < N_DST) offsets[r * N_DST + dst] = gbase + base_l[s];
    cnt[s] = 0;
  }
  __syncthreads();
  for (int e = gbase + tid; e < gend; e += 256) {
    unsigned w = tmp[e];
    int s = w >> 17;
    int pos = gbase + base_l[s] + atomicAdd(&cnt[s], 1);
    src_sorted[pos] = (int)(w & 0x1FFFFu);
  }
}

// ---------------- GAT aggregation: one wave per (relation, dst-node) ----------------
// 4 groups of 16 lanes process 4 edges concurrently (16 lanes x 8B = one fp16 row).
// Cuts the serial per-edge broadcast chain 4x and halves gather bytes vs f32.
__global__ __launch_bounds__(256) void k_aggregate(
    const int* __restrict__ offsets, const int* __restrict__ src_sorted,
    const float* __restrict__ el, const float* __restrict__ er,
    const __half* __restrict__ h16, float* __restrict__ zbuf) {
  int gw = (blockIdx.x * 256 + threadIdx.x) >> 6;
  int lane = threadIdx.x & 63;
  if (gw >= RREL * N_DST) return;
  int r = gw / N_DST;
  int start = offsets[gw], end = offsets[gw + 1];
  float erv = er[gw];
  const __half* hs = h16 + (size_t)r * N_DST * HDIM;
  const float* elr = el + (size_t)r * N_DST;
  int g = lane >> 4;   // group 0..3 (edge slot within a 4-edge iteration)
  int li = lane & 15;  // lane-in-group: h-dims 4*li .. 4*li+3
  float ax = 0.f, ay = 0.f, az = 0.f, aw = 0.f;
  float ssum = 0.f;
  for (int base = start; base < end; base += 64) {
    int cnt = end - base;
    if (cnt > 64) cnt = 64;
    float a = 0.f;
    int sidx = 0;
    if (lane < cnt) {
      sidx = src_sorted[base + lane];
      float x = elr[sidx] + erv;
      x = (x > 0.f) ? x : 0.01f * x;  // leaky_relu
      a = __expf(x);
    }
    ssum += a;
    int iters = (cnt + 3) >> 2;
    for (int i = 0; i < iters; i++) {
      int j = 4 * i + g;
      float aj = __shfl(a, j);
      int sj = __shfl(sidx, j);
      if (j < cnt) {
        float2 rv = *(const float2*)(hs + ((size_t)sj << 6) + 4 * li);
        float2 lo = __half22float2(*(const __half2*)&rv.x);
        float2 hi = __half22float2(*(const __half2*)&rv.y);
        ax += aj * lo.x;
        ay += aj * lo.y;
        az += aj * hi.x;
        aw += aj * hi.y;
      }
    }
  }
#pragma unroll
  for (int o = 32; o > 0; o >>= 1) ssum += __shfl_xor(ssum, o);
  // combine the 4 groups' partial sums (lanes with equal li share h-range)
#pragma unroll
  for (int o = 16; o <= 32; o <<= 1) {
    ax += __shfl_xor(ax, o);
    ay += __shfl_xor(ay, o);
    az += __shfl_xor(az, o);
    aw += __shfl_xor(aw, o);
  }
  if (g == 0) {
    float4 zv = make_float4(0.f, 0.f, 0.f, 0.f);
    if (end > start) {
      float inv = 1.f / ssum;
      float v;
      v = ax * inv; zv.x = (v > 0.f) ? v : (__expf(v) - 1.f);  // elu
      v = ay * inv; zv.y = (v > 0.f) ? v : (__expf(v) - 1.f);
      v = az * inv; zv.z = (v > 0.f) ? v : (__expf(v) - 1.f);
      v = aw * inv; zv.w = (v > 0.f) ? v : (__expf(v) - 1.f);
    }
    *(float4*)(zbuf + (size_t)gw * HDIM + 4 * li) = zv;
  }
}

// ---------------- semantic attention reduce ----------------
// jj loop NOT fully unrolled (full unroll spilled: 256 VGPR + 1.5 GB scratch traffic).
__global__ __launch_bounds__(256) void k_semantic(
    const float* __restrict__ zbuf, const float* __restrict__ W1,
    const float* __restrict__ b1, const float* __restrict__ w2,
    float* __restrict__ w_acc) {
  __shared__ float W1l[64 * 128];  // 32 KB
  __shared__ float zsh[64 * 68];   // 17.4 KB, +4 pad
  __shared__ float wsum[RREL];
  int tid = threadIdx.x;
  if (tid < RREL) wsum[tid] = 0.f;
  for (int i = tid * 4; i < 64 * 128; i += 1024)
    *(float4*)(W1l + i) = *(const float4*)(W1 + i);
  long row0 = (long)blockIdx.x * 64;
  for (int t4 = tid; t4 < 1024; t4 += 256) {
    int rl = t4 >> 4;
    int j4 = (t4 & 15) << 2;
    long row = row0 + rl;
    float4 v = make_float4(0.f, 0.f, 0.f, 0.f);
    if (row < (long)NSEG) v = *(const float4*)(zbuf + row * HDIM + j4);
    *(float4*)(zsh + rl * 68 + j4) = v;
  }
  __syncthreads();
  int tc = tid & 31;
  int tr = tid >> 5;
  float acc[8][4] = {};
#pragma unroll 1
  for (int jj = 0; jj < 64; jj += 4) {
    float4 wv[4];
#pragma unroll
    for (int j = 0; j < 4; j++) wv[j] = *(float4*)(W1l + (jj + j) * 128 + 4 * tc);
#pragma unroll
    for (int ih = 0; ih < 2; ih++) {
      float4 zv[4];
#pragma unroll
      for (int i = 0; i < 4; i++) zv[i] = *(float4*)(zsh + (8 * tr + 4 * ih + i) * 68 + jj);
#pragma unroll
      for (int i = 0; i < 4; i++) {
        const float* zp = (const float*)&zv[i];
#pragma unroll
        for (int j = 0; j < 4; j++) {
          const float* wp = (const float*)&wv[j];
          float zz = zp[j];
#pragma unroll
          for (int c = 0; c < 4; c++) acc[4 * ih + i][c] += zz * wp[c];
        }
      }
    }
  }
  float b1v[4], w2v[4];
#pragma unroll
  for (int c = 0; c < 4; c++) {
    b1v[c] = b1[4 * tc + c];
    w2v[c] = w2[4 * tc + c];
  }
#pragma unroll
  for (int i = 0; i < 8; i++) {
    long row = row0 + 8 * tr + i;
    float p = 0.f;
#pragma unroll
    for (int c = 0; c < 4; c++) {
      float x = acc[i][c] + b1v[c];
      float ex = __expf(2.f * x);
      p += (1.f - 2.f / (ex + 1.f)) * w2v[c];  // tanh
    }
#pragma unroll
    for (int o = 16; o > 0; o >>= 1) p += __shfl_xor(p, o);
    if (tc == 0 && row < (long)NSEG) {
      int r = (int)(row / N_DST);
      atomicAdd(&wsum[r], p);
    }
  }
  __syncthreads();
  if (tid < RREL) atomicAdd(&w_acc[tid], wsum[tid]);
}

// ---------------- softmax over relations + weighted combine ----------------
__global__ __launch_bounds__(256) void k_final(const float* __restrict__ zbuf,
                                               const float* __restrict__ w_acc,
                                               float* __restrict__ out) {
  int idx = blockIdx.x * 256 + threadIdx.x;
  if (idx >= N_DST * HDIM / 4) return;
  const float invN = 1.0f / N_DST;
  float w0 = w_acc[0] * invN, w1 = w_acc[1] * invN, w2v = w_acc[2] * invN;
  float m = fmaxf(w0, fmaxf(w1, w2v));
  float e0 = __expf(w0 - m), e1 = __expf(w1 - m), e2 = __expf(w2v - m);
  float inv = 1.f / (e0 + e1 + e2);
  e0 *= inv; e1 *= inv; e2 *= inv;
  size_t o = (size_t)idx * 4;
  const size_t stride = (size_t)N_DST * HDIM;
  float4 z0 = *(const float4*)(zbuf + o);
  float4 z1 = *(const float4*)(zbuf + stride + o);
  float4 z2 = *(const float4*)(zbuf + 2 * stride + o);
  float4 r;
  r.x = e0 * z0.x + e1 * z1.x + e2 * z2.x;
  r.y = e0 * z0.y + e1 * z1.y + e2 * z2.y;
  r.z = e0 * z0.z + e1 * z1.z + e2 * z2.z;
  r.w = e0 * z0.w + e1 * z1.w + e2 * z2.w;
  *(float4*)(out + o) = r;
}

extern "C" void kernel_launch(void* const* d_in, const int* in_sizes, int n_in,
                              void* d_out, int out_size, void* d_ws, size_t ws_size,
                              hipStream_t stream) {
  const float* dst_feat = (const float*)d_in[0];
  const float* neigh = (const float*)d_in[1];
  const float* Wt = (const float*)d_in[2];
  const float* bt = (const float*)d_in[3];
  const float* attn_l = (const float*)d_in[4];
  const float* attn_r = (const float*)d_in[5];
  const float* W1 = (const float*)d_in[6];
  const float* b1 = (const float*)d_in[7];
  const float* w2 = (const float*)d_in[8];
  const int* src_idx = (const int*)d_in[9];
  const int* dst_idx = (const int*)d_in[10];
  float* out = (float*)d_out;

  char* p = (char*)d_ws;
  auto alloc = [&](size_t bytes) {
    char* q = p;
    p += (bytes + 255) & ~(size_t)255;
    return (void*)q;
  };
  __half* h16 = (__half*)alloc((size_t)RREL * N_DST * HDIM * 2);
  float* el = (float*)alloc((size_t)RREL * N_DST * 4);
  float* er = (float*)alloc((size_t)RREL * N_DST * 4);
  float* zbuf = (float*)alloc((size_t)RREL * N_DST * HDIM * 4);
  float* w_acc = (float*)alloc(64);
  int* offsets = (int*)alloc(((size_t)NSEG + 1) * 4);
  int* hist = (int*)alloc((size_t)NBKT * NBLK_BIN * 4);
  int* bcounts = (int*)alloc((size_t)NBKT * 4);
  int* bucket_base = (int*)alloc((size_t)(NBKT + 1) * 4);
  unsigned* tmp = (unsigned*)alloc((size_t)RREL * NE * 4);
  int* src_sorted = (int*)alloc((size_t)RREL * NE * 4);

  hipMemsetAsync(w_acc, 0, 64, stream);

  k_gemm<<<4 * ((N_DST + 63) / 64), 256, 0, stream>>>(dst_feat, neigh, Wt, bt, attn_l, attn_r,
                                                      h16, el, er);
  k_hist<<<NBLK_BIN, 256, 0, stream>>>(dst_idx, hist);
  k_colscan<<<NBKT, 256, 0, stream>>>(hist, bcounts);
  k_bscan<<<1, 256, 0, stream>>>(bcounts, bucket_base, offsets);
  k_place<<<NBLK_BIN, 256, 0, stream>>>(src_idx, dst_idx, hist, bucket_base, tmp);
  k_bucket_csr<<<NBKT, 256, 0, stream>>>(bucket_base, tmp, src_sorted, offsets);
  k_aggregate<<<(RREL * N_DST * 64) / 256, 256, 0, stream>>>(offsets, src_sorted, el, er, h16, zbuf);
  k_semantic<<<(NSEG + 63) / 64, 256, 0, stream>>>(zbuf, W1, b1, w2, w_acc);
  k_final<<<(N_DST * HDIM / 4 + 255) / 256, 256, 0, stream>>>(zbuf, w_acc, out);
}

// Round 3
// 608.046 us; speedup vs baseline: 1.3266x; 1.0886x over previous
//
#include <hip/hip_runtime.h>
#include <hip/hip_fp16.h>

#define N_DST 100000
#define DIN 128
#define HDIM 64
#define RREL 3
#define NE 1000000

#define NBKT_REL 196              // ceil(100000/512) buckets per relation
#define NBKT (RREL * NBKT_REL)    // 588 total buckets
#define NSEG (RREL * N_DST)       // 300000 segments
#define EDGE_CHUNK 16384
#define NBLK_BIN ((RREL * NE + EDGE_CHUNK - 1) / EDGE_CHUNK)  // 184

typedef _Float16 f16x8 __attribute__((ext_vector_type(8)));
typedef float f32x4 __attribute__((ext_vector_type(4)));

// ---------------- GEMM via MFMA: h = A @ W + b  (4 matrices: dst + 3 relations) ----
// fp16 inputs (error ~5e-4, same order as the fp16 h16 store we already do),
// f32 accumulate on matrix cores. Block tile 128 rows x 64 cols, K=128 staged once.
// LDS fp16 tiles XOR-swizzled (byte ^= (row&7)<<4) so stride-256B ds_read_b128
// fragment reads are 2-way (free) instead of 16-way bank conflicts.
// Epilogue: bias add + el/er logits via 16-lane xor-reduce; fp16 h store (rel mats).
__global__ __launch_bounds__(256) void k_gemm(
    const float* __restrict__ dst_feat, const float* __restrict__ neigh,
    const float* __restrict__ Wt, const float* __restrict__ bt,
    const float* __restrict__ attn_l, const float* __restrict__ attn_r,
    __half* __restrict__ h16, float* __restrict__ el, float* __restrict__ er) {
  const int RB = (N_DST + 127) / 128;  // 782 row-blocks per matrix
  int mat = blockIdx.x / RB;
  int row0 = (blockIdx.x % RB) * 128;
  const float* A = (mat == 0) ? dst_feat : (neigh + (size_t)(mat - 1) * N_DST * DIN);
  const float* W = Wt + (size_t)mat * DIN * HDIM;  // [k=128][n=64]
  const float* b = bt + mat * HDIM;

  __shared__ __align__(16) unsigned char lds[48 * 1024];
  unsigned char* ldsA = lds;           // 128 rows x 128 k fp16 = 32 KB (swizzled)
  unsigned char* ldsW = lds + 32768;   // 64 cols x 128 k fp16 = 16 KB (swizzled)

  int tid = threadIdx.x;

  // ---- stage A: 128x128 f32 -> fp16 LDS (row-major in k, swizzled) ----
#pragma unroll
  for (int i = 0; i < 8; i++) {
    int s = tid + 256 * i;  // 0..2047
    int row = s >> 4;       // 0..127
    int kb = s & 15;        // 16B (8 fp16) block along k
    int gr = row0 + row;
    if (gr >= N_DST) gr = N_DST - 1;  // clamp (tail block)
    const float* ap = A + (size_t)gr * DIN + kb * 8;
    float4 v0 = *(const float4*)ap;
    float4 v1 = *(const float4*)(ap + 4);
    f16x8 hv;
    hv[0] = (_Float16)v0.x; hv[1] = (_Float16)v0.y;
    hv[2] = (_Float16)v0.z; hv[3] = (_Float16)v0.w;
    hv[4] = (_Float16)v1.x; hv[5] = (_Float16)v1.y;
    hv[6] = (_Float16)v1.z; hv[7] = (_Float16)v1.w;
    *(f16x8*)(ldsA + row * 256 + ((kb * 16) ^ ((row & 7) << 4))) = hv;
  }

  // ---- stage W transposed: [k][n] f32 -> [n][k] fp16 LDS (swizzled) ----
  {
    int col = tid & 63;  // wave lanes cover cols 0..63 -> coalesced 256B rows
    int kq = tid >> 6;   // 0..3 (k chunk of 32)
    const float* wp = W + (size_t)(kq * 32) * HDIM + col;
    float wr[32];
#pragma unroll
    for (int m = 0; m < 32; m++) wr[m] = wp[(size_t)m * HDIM];
#pragma unroll
    for (int m8 = 0; m8 < 4; m8++) {
      f16x8 hv;
#pragma unroll
      for (int j = 0; j < 8; j++) hv[j] = (_Float16)wr[m8 * 8 + j];
      int byt = kq * 64 + m8 * 16;  // = k*2
      *(f16x8*)(ldsW + col * 256 + (byt ^ ((col & 7) << 4))) = hv;
    }
  }
  __syncthreads();

  // ---- MFMA: wave w owns rows w*32..w*32+31 (2 M-tiles) x 64 cols (4 N-tiles) ----
  int w = tid >> 6;
  int l = tid & 63;
  int li = l & 15;   // fragment row/col within tile
  int hi = l >> 4;   // k-quarter within fragment
  f32x4 acc[2][4] = {};
#pragma unroll
  for (int ks = 0; ks < 4; ks++) {
    int kbyte = ks * 64 + hi * 16;
    f16x8 af[2], bf[4];
#pragma unroll
    for (int rt = 0; rt < 2; rt++) {
      int row = w * 32 + rt * 16 + li;
      af[rt] = *(f16x8*)(ldsA + row * 256 + (kbyte ^ ((row & 7) << 4)));
    }
#pragma unroll
    for (int ct = 0; ct < 4; ct++) {
      int col = ct * 16 + li;
      bf[ct] = *(f16x8*)(ldsW + col * 256 + (kbyte ^ ((col & 7) << 4)));
    }
#pragma unroll
    for (int rt = 0; rt < 2; rt++)
#pragma unroll
      for (int ct = 0; ct < 4; ct++)
        acc[rt][ct] = __builtin_amdgcn_mfma_f32_16x16x32_f16(af[rt], bf[ct], acc[rt][ct], 0, 0, 0);
  }

  // ---- epilogue: bias, logits, fp16 h store ----
  // C/D layout: col = ct*16 + li, row(local) = w*32 + rt*16 + hi*4 + j
  float bv[4];
#pragma unroll
  for (int ct = 0; ct < 4; ct++) bv[ct] = b[ct * 16 + li];
#pragma unroll
  for (int rt = 0; rt < 2; rt++)
#pragma unroll
    for (int ct = 0; ct < 4; ct++)
#pragma unroll
      for (int j = 0; j < 4; j++) acc[rt][ct][j] += bv[ct];

  if (mat == 0) {
    // er[r][n] = h_dst[n] . attn_r[r]
#pragma unroll
    for (int r = 0; r < RREL; r++) {
      float av[4];
#pragma unroll
      for (int ct = 0; ct < 4; ct++) av[ct] = attn_r[r * HDIM + ct * 16 + li];
#pragma unroll
      for (int rt = 0; rt < 2; rt++) {
        float p[4];
#pragma unroll
        for (int j = 0; j < 4; j++)
          p[j] = acc[rt][0][j] * av[0] + acc[rt][1][j] * av[1] +
                 acc[rt][2][j] * av[2] + acc[rt][3][j] * av[3];
#pragma unroll
        for (int o = 1; o < 16; o <<= 1)
#pragma unroll
          for (int j = 0; j < 4; j++) p[j] += __shfl_xor(p[j], o);
        if (li == 0) {
#pragma unroll
          for (int j = 0; j < 4; j++) {
            int gr = row0 + w * 32 + rt * 16 + hi * 4 + j;
            if (gr < N_DST) er[r * N_DST + gr] = p[j];
          }
        }
      }
    }
  } else {
    int r = mat - 1;
    float av[4];
#pragma unroll
    for (int ct = 0; ct < 4; ct++) av[ct] = attn_l[r * HDIM + ct * 16 + li];
#pragma unroll
    for (int rt = 0; rt < 2; rt++) {
      float p[4];
#pragma unroll
      for (int j = 0; j < 4; j++)
        p[j] = acc[rt][0][j] * av[0] + acc[rt][1][j] * av[1] +
               acc[rt][2][j] * av[2] + acc[rt][3][j] * av[3];
#pragma unroll
      for (int o = 1; o < 16; o <<= 1)
#pragma unroll
        for (int j = 0; j < 4; j++) p[j] += __shfl_xor(p[j], o);
      if (li == 0) {
#pragma unroll
        for (int j = 0; j < 4; j++) {
          int gr = row0 + w * 32 + rt * 16 + hi * 4 + j;
          if (gr < N_DST) el[r * N_DST + gr] = p[j];
        }
      }
    }
    __half* hb = h16 + (size_t)r * N_DST * HDIM;
#pragma unroll
    for (int rt = 0; rt < 2; rt++)
#pragma unroll
      for (int j = 0; j < 4; j++) {
        int gr = row0 + w * 32 + rt * 16 + hi * 4 + j;
        if (gr < N_DST) {
#pragma unroll
          for (int ct = 0; ct < 4; ct++)
            hb[(size_t)gr * HDIM + ct * 16 + li] = __float2half(acc[rt][ct][j]);
        }
      }
  }
}

// ---------------- CSR build: counting-sort partition, zero global atomics ----------------
// Buckets: (relation, dst>>9) -> 588 buckets of 512 dst nodes; bucket order == segment order.

// 1) per-chunk histogram -> hist[bucket][block] (bucket-major)
__global__ __launch_bounds__(256) void k_hist(const int* __restrict__ dst_idx,
                                              int* __restrict__ hist) {
  __shared__ int h[NBKT];
  int tid = threadIdx.x;
  int blk = blockIdx.x;
  for (int i = tid; i < NBKT; i += 256) h[i] = 0;
  __syncthreads();
  int e0 = blk * EDGE_CHUNK;
  int e1 = min(e0 + EDGE_CHUNK, RREL * NE);
  for (int idx = e0 + tid; idx < e1; idx += 256) {
    int r = idx / NE;
    int d = dst_idx[idx];
    atomicAdd(&h[r * NBKT_REL + (d >> 9)], 1);
  }
  __syncthreads();
  for (int i = tid; i < NBKT; i += 256)
    hist[(size_t)i * NBLK_BIN + blk] = h[i];
}

// 2) per-bucket exclusive scan across blocks; bucket totals out
__global__ __launch_bounds__(256) void k_colscan(int* __restrict__ hist,
                                                 int* __restrict__ bcounts) {
  __shared__ int sm[256];
  int b = blockIdx.x;
  int tid = threadIdx.x;
  int v = (tid < NBLK_BIN) ? hist[(size_t)b * NBLK_BIN + tid] : 0;
  sm[tid] = v;
  __syncthreads();
  for (int off = 1; off < 256; off <<= 1) {
    int t = (tid >= off) ? sm[tid - off] : 0;
    __syncthreads();
    sm[tid] += t;
    __syncthreads();
  }
  if (tid < NBLK_BIN) hist[(size_t)b * NBLK_BIN + tid] = sm[tid] - v;  // exclusive
  if (tid == 255) bcounts[b] = sm[255];
}

// 3) scan 588 bucket totals -> bucket_base[589]; offsets[NSEG]=3M
__global__ __launch_bounds__(256) void k_bscan(const int* __restrict__ bcounts,
                                               int* __restrict__ bucket_base,
                                               int* __restrict__ offsets) {
  __shared__ int sm[256];
  int tid = threadIdx.x;
  int base = tid * 3;
  int c[3];
#pragma unroll
  for (int k = 0; k < 3; k++) c[k] = (base + k < NBKT) ? bcounts[base + k] : 0;
  int tsum = c[0] + c[1] + c[2];
  sm[tid] = tsum;
  __syncthreads();
  for (int off = 1; off < 256; off <<= 1) {
    int v = (tid >= off) ? sm[tid - off] : 0;
    __syncthreads();
    sm[tid] += v;
    __syncthreads();
  }
  int run = sm[tid] - tsum;
#pragma unroll
  for (int k = 0; k < 3; k++) {
    if (base + k < NBKT) bucket_base[base + k] = run;
    run += c[k];
  }
  if (tid == 255) bucket_base[NBKT] = sm[255];  // = RREL*NE
  if (tid == 0) offsets[NSEG] = RREL * NE;
}

// 4) place edges: per-block LDS cursors seeded from scanned bases; LDS atomics only.
//    Packed word (localdst<<17 | src); src < 2^17, localdst < 2^9.
__global__ __launch_bounds__(256) void k_place(const int* __restrict__ src_idx,
                                               const int* __restrict__ dst_idx,
                                               const int* __restrict__ hist,
                                               const int* __restrict__ bucket_base,
                                               unsigned* __restrict__ tmp) {
  __shared__ int cur[NBKT];
  int tid = threadIdx.x;
  int blk = blockIdx.x;
  for (int i = tid; i < NBKT; i += 256)
    cur[i] = bucket_base[i] + hist[(size_t)i * NBLK_BIN + blk];
  __syncthreads();
  int e0 = blk * EDGE_CHUNK;
  int e1 = min(e0 + EDGE_CHUNK, RREL * NE);
  for (int idx = e0 + tid; idx < e1; idx += 256) {
    int r = idx / NE;
    int d = dst_idx[idx];
    int s = src_idx[idx];
    int bucket = r * NBKT_REL + (d >> 9);
    int pos = atomicAdd(&cur[bucket], 1);
    tmp[pos] = ((unsigned)(d & 511) << 17) | (unsigned)s;
  }
}

// 5) per-bucket: LDS histogram of 512 local segments + block scan -> per-segment
//    offsets + final scatter (random writes confined to ~20 KB -> L2-combined).
__global__ __launch_bounds__(256) void k_bucket_csr(
    const int* __restrict__ bucket_base, const unsigned* __restrict__ tmp,
    int* __restrict__ src_sorted, int* __restrict__ offsets) {
  __shared__ int cnt[512];
  __shared__ int base_l[512];
  __shared__ int sm[256];
  int b = blockIdx.x;
  int r = b / NBKT_REL;
  int brel = b - r * NBKT_REL;
  int gbase = bucket_base[b];
  int gend = bucket_base[b + 1];
  int tid = threadIdx.x;
  cnt[tid] = 0;
  cnt[tid + 256] = 0;
  __syncthreads();
  for (int e = gbase + tid; e < gend; e += 256)
    atomicAdd(&cnt[tmp[e] >> 17], 1);
  __syncthreads();
  int c0 = cnt[2 * tid], c1 = cnt[2 * tid + 1];
  int tsum = c0 + c1;
  sm[tid] = tsum;
  __syncthreads();
  for (int off = 1; off < 256; off <<= 1) {
    int v = (tid >= off) ? sm[tid - off] : 0;
    __syncthreads();
    sm[tid] += v;
    __syncthreads();
  }
  int run = sm[tid] - tsum;
  base_l[2 * tid] = run;
  base_l[2 * tid + 1] = run + c0;
  __syncthreads();
  for (int s = tid; s < 512; s += 256) {
    int dst = (brel << 9) + s;
    if (dst < N_DST) offsets[r * N_DST + dst] = gbase + base_l[s];
    cnt[s] = 0;
  }
  __syncthreads();
  for (int e = gbase + tid; e < gend; e += 256) {
    unsigned w = tmp[e];
    int s = w >> 17;
    int pos = gbase + base_l[s] + atomicAdd(&cnt[s], 1);
    src_sorted[pos] = (int)(w & 0x1FFFFu);
  }
}

// ---------------- GAT aggregation: one wave per (relation, dst-node) ----------------
// 4 groups of 16 lanes process 4 edges concurrently (16 lanes x 8B = one fp16 row).
// Cuts the serial per-edge broadcast chain 4x and halves gather bytes vs f32.
__global__ __launch_bounds__(256) void k_aggregate(
    const int* __restrict__ offsets, const int* __restrict__ src_sorted,
    const float* __restrict__ el, const float* __restrict__ er,
    const __half* __restrict__ h16, float* __restrict__ zbuf) {
  int gw = (blockIdx.x * 256 + threadIdx.x) >> 6;
  int lane = threadIdx.x & 63;
  if (gw >= RREL * N_DST) return;
  int r = gw / N_DST;
  int start = offsets[gw], end = offsets[gw + 1];
  float erv = er[gw];
  const __half* hs = h16 + (size_t)r * N_DST * HDIM;
  const float* elr = el + (size_t)r * N_DST;
  int g = lane >> 4;   // group 0..3 (edge slot within a 4-edge iteration)
  int li = lane & 15;  // lane-in-group: h-dims 4*li .. 4*li+3
  float ax = 0.f, ay = 0.f, az = 0.f, aw = 0.f;
  float ssum = 0.f;
  for (int base = start; base < end; base += 64) {
    int cnt = end - base;
    if (cnt > 64) cnt = 64;
    float a = 0.f;
    int sidx = 0;
    if (lane < cnt) {
      sidx = src_sorted[base + lane];
      float x = elr[sidx] + erv;
      x = (x > 0.f) ? x : 0.01f * x;  // leaky_relu
      a = __expf(x);
    }
    ssum += a;
    int iters = (cnt + 3) >> 2;
    for (int i = 0; i < iters; i++) {
      int j = 4 * i + g;
      float aj = __shfl(a, j);
      int sj = __shfl(sidx, j);
      if (j < cnt) {
        float2 rv = *(const float2*)(hs + ((size_t)sj << 6) + 4 * li);
        float2 lo = __half22float2(*(const __half2*)&rv.x);
        float2 hi = __half22float2(*(const __half2*)&rv.y);
        ax += aj * lo.x;
        ay += aj * lo.y;
        az += aj * hi.x;
        aw += aj * hi.y;
      }
    }
  }
#pragma unroll
  for (int o = 32; o > 0; o >>= 1) ssum += __shfl_xor(ssum, o);
  // combine the 4 groups' partial sums (lanes with equal li share h-range)
#pragma unroll
  for (int o = 16; o <= 32; o <<= 1) {
    ax += __shfl_xor(ax, o);
    ay += __shfl_xor(ay, o);
    az += __shfl_xor(az, o);
    aw += __shfl_xor(aw, o);
  }
  if (g == 0) {
    float4 zv = make_float4(0.f, 0.f, 0.f, 0.f);
    if (end > start) {
      float inv = 1.f / ssum;
      float v;
      v = ax * inv; zv.x = (v > 0.f) ? v : (__expf(v) - 1.f);  // elu
      v = ay * inv; zv.y = (v > 0.f) ? v : (__expf(v) - 1.f);
      v = az * inv; zv.z = (v > 0.f) ? v : (__expf(v) - 1.f);
      v = aw * inv; zv.w = (v > 0.f) ? v : (__expf(v) - 1.f);
    }
    *(float4*)(zbuf + (size_t)gw * HDIM + 4 * li) = zv;
  }
}

// ---------------- semantic attention reduce ----------------
// jj loop NOT fully unrolled (full unroll spilled: 256 VGPR + 1.5 GB scratch traffic).
__global__ __launch_bounds__(256) void k_semantic(
    const float* __restrict__ zbuf, const float* __restrict__ W1,
    const float* __restrict__ b1, const float* __restrict__ w2,
    float* __restrict__ w_acc) {
  __shared__ float W1l[64 * 128];  // 32 KB
  __shared__ float zsh[64 * 68];   // 17.4 KB, +4 pad
  __shared__ float wsum[RREL];
  int tid = threadIdx.x;
  if (tid < RREL) wsum[tid] = 0.f;
  for (int i = tid * 4; i < 64 * 128; i += 1024)
    *(float4*)(W1l + i) = *(const float4*)(W1 + i);
  long row0 = (long)blockIdx.x * 64;
  for (int t4 = tid; t4 < 1024; t4 += 256) {
    int rl = t4 >> 4;
    int j4 = (t4 & 15) << 2;
    long row = row0 + rl;
    float4 v = make_float4(0.f, 0.f, 0.f, 0.f);
    if (row < (long)NSEG) v = *(const float4*)(zbuf + row * HDIM + j4);
    *(float4*)(zsh + rl * 68 + j4) = v;
  }
  __syncthreads();
  int tc = tid & 31;
  int tr = tid >> 5;
  float acc[8][4] = {};
#pragma unroll 1
  for (int jj = 0; jj < 64; jj += 4) {
    float4 wv[4];
#pragma unroll
    for (int j = 0; j < 4; j++) wv[j] = *(float4*)(W1l + (jj + j) * 128 + 4 * tc);
#pragma unroll
    for (int ih = 0; ih < 2; ih++) {
      float4 zv[4];
#pragma unroll
      for (int i = 0; i < 4; i++) zv[i] = *(float4*)(zsh + (8 * tr + 4 * ih + i) * 68 + jj);
#pragma unroll
      for (int i = 0; i < 4; i++) {
        const float* zp = (const float*)&zv[i];
#pragma unroll
        for (int j = 0; j < 4; j++) {
          const float* wp = (const float*)&wv[j];
          float zz = zp[j];
#pragma unroll
          for (int c = 0; c < 4; c++) acc[4 * ih + i][c] += zz * wp[c];
        }
      }
    }
  }
  float b1v[4], w2v[4];
#pragma unroll
  for (int c = 0; c < 4; c++) {
    b1v[c] = b1[4 * tc + c];
    w2v[c] = w2[4 * tc + c];
  }
#pragma unroll
  for (int i = 0; i < 8; i++) {
    long row = row0 + 8 * tr + i;
    float p = 0.f;
#pragma unroll
    for (int c = 0; c < 4; c++) {
      float x = acc[i][c] + b1v[c];
      float ex = __expf(2.f * x);
      p += (1.f - 2.f / (ex + 1.f)) * w2v[c];  // tanh
    }
#pragma unroll
    for (int o = 16; o > 0; o >>= 1) p += __shfl_xor(p, o);
    if (tc == 0 && row < (long)NSEG) {
      int r = (int)(row / N_DST);
      atomicAdd(&wsum[r], p);
    }
  }
  __syncthreads();
  if (tid < RREL) atomicAdd(&w_acc[tid], wsum[tid]);
}

// ---------------- softmax over relations + weighted combine ----------------
__global__ __launch_bounds__(256) void k_final(const float* __restrict__ zbuf,
                                               const float* __restrict__ w_acc,
                                               float* __restrict__ out) {
  int idx = blockIdx.x * 256 + threadIdx.x;
  if (idx >= N_DST * HDIM / 4) return;
  const float invN = 1.0f / N_DST;
  float w0 = w_acc[0] * invN, w1 = w_acc[1] * invN, w2v = w_acc[2] * invN;
  float m = fmaxf(w0, fmaxf(w1, w2v));
  float e0 = __expf(w0 - m), e1 = __expf(w1 - m), e2 = __expf(w2v - m);
  float inv = 1.f / (e0 + e1 + e2);
  e0 *= inv; e1 *= inv; e2 *= inv;
  size_t o = (size_t)idx * 4;
  const size_t stride = (size_t)N_DST * HDIM;
  float4 z0 = *(const float4*)(zbuf + o);
  float4 z1 = *(const float4*)(zbuf + stride + o);
  float4 z2 = *(const float4*)(zbuf + 2 * stride + o);
  float4 r;
  r.x = e0 * z0.x + e1 * z1.x + e2 * z2.x;
  r.y = e0 * z0.y + e1 * z1.y + e2 * z2.y;
  r.z = e0 * z0.z + e1 * z1.z + e2 * z2.z;
  r.w = e0 * z0.w + e1 * z1.w + e2 * z2.w;
  *(float4*)(out + o) = r;
}

extern "C" void kernel_launch(void* const* d_in, const int* in_sizes, int n_in,
                              void* d_out, int out_size, void* d_ws, size_t ws_size,
                              hipStream_t stream) {
  const float* dst_feat = (const float*)d_in[0];
  const float* neigh = (const float*)d_in[1];
  const float* Wt = (const float*)d_in[2];
  const float* bt = (const float*)d_in[3];
  const float* attn_l = (const float*)d_in[4];
  const float* attn_r = (const float*)d_in[5];
  const float* W1 = (const float*)d_in[6];
  const float* b1 = (const float*)d_in[7];
  const float* w2 = (const float*)d_in[8];
  const int* src_idx = (const int*)d_in[9];
  const int* dst_idx = (const int*)d_in[10];
  float* out = (float*)d_out;

  char* p = (char*)d_ws;
  auto alloc = [&](size_t bytes) {
    char* q = p;
    p += (bytes + 255) & ~(size_t)255;
    return (void*)q;
  };
  __half* h16 = (__half*)alloc((size_t)RREL * N_DST * HDIM * 2);
  float* el = (float*)alloc((size_t)RREL * N_DST * 4);
  float* er = (float*)alloc((size_t)RREL * N_DST * 4);
  float* zbuf = (float*)alloc((size_t)RREL * N_DST * HDIM * 4);
  float* w_acc = (float*)alloc(64);
  int* offsets = (int*)alloc(((size_t)NSEG + 1) * 4);
  int* hist = (int*)alloc((size_t)NBKT * NBLK_BIN * 4);
  int* bcounts = (int*)alloc((size_t)NBKT * 4);
  int* bucket_base = (int*)alloc((size_t)(NBKT + 1) * 4);
  unsigned* tmp = (unsigned*)alloc((size_t)RREL * NE * 4);
  int* src_sorted = (int*)alloc((size_t)RREL * NE * 4);

  hipMemsetAsync(w_acc, 0, 64, stream);

  k_gemm<<<4 * ((N_DST + 127) / 128), 256, 0, stream>>>(dst_feat, neigh, Wt, bt, attn_l, attn_r,
                                                        h16, el, er);
  k_hist<<<NBLK_BIN, 256, 0, stream>>>(dst_idx, hist);
  k_colscan<<<NBKT, 256, 0, stream>>>(hist, bcounts);
  k_bscan<<<1, 256, 0, stream>>>(bcounts, bucket_base, offsets);
  k_place<<<NBLK_BIN, 256, 0, stream>>>(src_idx, dst_idx, hist, bucket_base, tmp);
  k_bucket_csr<<<NBKT, 256, 0, stream>>>(bucket_base, tmp, src_sorted, offsets);
  k_aggregate<<<(RREL * N_DST * 64) / 256, 256, 0, stream>>>(offsets, src_sorted, el, er, h16, zbuf);
  k_semantic<<<(NSEG + 63) / 64, 256, 0, stream>>>(zbuf, W1, b1, w2, w_acc);
  k_final<<<(N_DST * HDIM / 4 + 255) / 256, 256, 0, stream>>>(zbuf, w_acc, out);
}

// Round 4
// 545.890 us; speedup vs baseline: 1.4777x; 1.1139x over previous
//
#include <hip/hip_runtime.h>
#include <hip/hip_fp16.h>

#define N_DST 100000
#define DIN 128
#define HDIM 64
#define RREL 3
#define NE 1000000

#define NBKT_REL 196              // ceil(100000/512) buckets per relation
#define NBKT (RREL * NBKT_REL)    // 588 total buckets
#define NSEG (RREL * N_DST)       // 300000 segments
#define EDGE_CHUNK 16384
#define NBLK_BIN ((RREL * NE + EDGE_CHUNK - 1) / EDGE_CHUNK)  // 184

typedef _Float16 f16x8 __attribute__((ext_vector_type(8)));
typedef float f32x4 __attribute__((ext_vector_type(4)));

// ---------------- GEMM via MFMA: h = A @ W + b  (4 matrices: dst + 3 relations) ----
// fp16 inputs (error ~5e-4, same order as the fp16 h16 store we already do),
// f32 accumulate on matrix cores. Block tile 128 rows x 64 cols, K=128 staged once.
// LDS fp16 tiles XOR-swizzled (byte ^= (row&7)<<4) so stride-256B ds_read_b128
// fragment reads are 2-way (free) instead of 16-way bank conflicts.
// Epilogue: bias add + el/er logits via 16-lane xor-reduce; fp16 h store (rel mats).
__global__ __launch_bounds__(256) void k_gemm(
    const float* __restrict__ dst_feat, const float* __restrict__ neigh,
    const float* __restrict__ Wt, const float* __restrict__ bt,
    const float* __restrict__ attn_l, const float* __restrict__ attn_r,
    __half* __restrict__ h16, float* __restrict__ el, float* __restrict__ er) {
  const int RB = (N_DST + 127) / 128;  // 782 row-blocks per matrix
  int mat = blockIdx.x / RB;
  int row0 = (blockIdx.x % RB) * 128;
  const float* A = (mat == 0) ? dst_feat : (neigh + (size_t)(mat - 1) * N_DST * DIN);
  const float* W = Wt + (size_t)mat * DIN * HDIM;  // [k=128][n=64]
  const float* b = bt + mat * HDIM;

  __shared__ __align__(16) unsigned char lds[48 * 1024];
  unsigned char* ldsA = lds;           // 128 rows x 128 k fp16 = 32 KB (swizzled)
  unsigned char* ldsW = lds + 32768;   // 64 cols x 128 k fp16 = 16 KB (swizzled)

  int tid = threadIdx.x;

  // ---- stage A: 128x128 f32 -> fp16 LDS (row-major in k, swizzled) ----
#pragma unroll
  for (int i = 0; i < 8; i++) {
    int s = tid + 256 * i;  // 0..2047
    int row = s >> 4;       // 0..127
    int kb = s & 15;        // 16B (8 fp16) block along k
    int gr = row0 + row;
    if (gr >= N_DST) gr = N_DST - 1;  // clamp (tail block)
    const float* ap = A + (size_t)gr * DIN + kb * 8;
    float4 v0 = *(const float4*)ap;
    float4 v1 = *(const float4*)(ap + 4);
    f16x8 hv;
    hv[0] = (_Float16)v0.x; hv[1] = (_Float16)v0.y;
    hv[2] = (_Float16)v0.z; hv[3] = (_Float16)v0.w;
    hv[4] = (_Float16)v1.x; hv[5] = (_Float16)v1.y;
    hv[6] = (_Float16)v1.z; hv[7] = (_Float16)v1.w;
    *(f16x8*)(ldsA + row * 256 + ((kb * 16) ^ ((row & 7) << 4))) = hv;
  }

  // ---- stage W transposed: [k][n] f32 -> [n][k] fp16 LDS (swizzled) ----
  {
    int col = tid & 63;  // wave lanes cover cols 0..63 -> coalesced 256B rows
    int kq = tid >> 6;   // 0..3 (k chunk of 32)
    const float* wp = W + (size_t)(kq * 32) * HDIM + col;
    float wr[32];
#pragma unroll
    for (int m = 0; m < 32; m++) wr[m] = wp[(size_t)m * HDIM];
#pragma unroll
    for (int m8 = 0; m8 < 4; m8++) {
      f16x8 hv;
#pragma unroll
      for (int j = 0; j < 8; j++) hv[j] = (_Float16)wr[m8 * 8 + j];
      int byt = kq * 64 + m8 * 16;  // = k*2
      *(f16x8*)(ldsW + col * 256 + (byt ^ ((col & 7) << 4))) = hv;
    }
  }
  __syncthreads();

  // ---- MFMA: wave w owns rows w*32..w*32+31 (2 M-tiles) x 64 cols (4 N-tiles) ----
  int w = tid >> 6;
  int l = tid & 63;
  int li = l & 15;   // fragment row/col within tile
  int hi = l >> 4;   // k-quarter within fragment
  f32x4 acc[2][4] = {};
#pragma unroll
  for (int ks = 0; ks < 4; ks++) {
    int kbyte = ks * 64 + hi * 16;
    f16x8 af[2], bf[4];
#pragma unroll
    for (int rt = 0; rt < 2; rt++) {
      int row = w * 32 + rt * 16 + li;
      af[rt] = *(f16x8*)(ldsA + row * 256 + (kbyte ^ ((row & 7) << 4)));
    }
#pragma unroll
    for (int ct = 0; ct < 4; ct++) {
      int col = ct * 16 + li;
      bf[ct] = *(f16x8*)(ldsW + col * 256 + (kbyte ^ ((col & 7) << 4)));
    }
#pragma unroll
    for (int rt = 0; rt < 2; rt++)
#pragma unroll
      for (int ct = 0; ct < 4; ct++)
        acc[rt][ct] = __builtin_amdgcn_mfma_f32_16x16x32_f16(af[rt], bf[ct], acc[rt][ct], 0, 0, 0);
  }

  // ---- epilogue: bias, logits, fp16 h store ----
  // C/D layout: col = ct*16 + li, row(local) = w*32 + rt*16 + hi*4 + j
  float bv[4];
#pragma unroll
  for (int ct = 0; ct < 4; ct++) bv[ct] = b[ct * 16 + li];
#pragma unroll
  for (int rt = 0; rt < 2; rt++)
#pragma unroll
    for (int ct = 0; ct < 4; ct++)
#pragma unroll
      for (int j = 0; j < 4; j++) acc[rt][ct][j] += bv[ct];

  if (mat == 0) {
    // er[r][n] = h_dst[n] . attn_r[r]
#pragma unroll
    for (int r = 0; r < RREL; r++) {
      float av[4];
#pragma unroll
      for (int ct = 0; ct < 4; ct++) av[ct] = attn_r[r * HDIM + ct * 16 + li];
#pragma unroll
      for (int rt = 0; rt < 2; rt++) {
        float p[4];
#pragma unroll
        for (int j = 0; j < 4; j++)
          p[j] = acc[rt][0][j] * av[0] + acc[rt][1][j] * av[1] +
                 acc[rt][2][j] * av[2] + acc[rt][3][j] * av[3];
#pragma unroll
        for (int o = 1; o < 16; o <<= 1)
#pragma unroll
          for (int j = 0; j < 4; j++) p[j] += __shfl_xor(p[j], o);
        if (li == 0) {
#pragma unroll
          for (int j = 0; j < 4; j++) {
            int gr = row0 + w * 32 + rt * 16 + hi * 4 + j;
            if (gr < N_DST) er[r * N_DST + gr] = p[j];
          }
        }
      }
    }
  } else {
    int r = mat - 1;
    float av[4];
#pragma unroll
    for (int ct = 0; ct < 4; ct++) av[ct] = attn_l[r * HDIM + ct * 16 + li];
#pragma unroll
    for (int rt = 0; rt < 2; rt++) {
      float p[4];
#pragma unroll
      for (int j = 0; j < 4; j++)
        p[j] = acc[rt][0][j] * av[0] + acc[rt][1][j] * av[1] +
               acc[rt][2][j] * av[2] + acc[rt][3][j] * av[3];
#pragma unroll
      for (int o = 1; o < 16; o <<= 1)
#pragma unroll
        for (int j = 0; j < 4; j++) p[j] += __shfl_xor(p[j], o);
      if (li == 0) {
#pragma unroll
        for (int j = 0; j < 4; j++) {
          int gr = row0 + w * 32 + rt * 16 + hi * 4 + j;
          if (gr < N_DST) el[r * N_DST + gr] = p[j];
        }
      }
    }
    __half* hb = h16 + (size_t)r * N_DST * HDIM;
#pragma unroll
    for (int rt = 0; rt < 2; rt++)
#pragma unroll
      for (int j = 0; j < 4; j++) {
        int gr = row0 + w * 32 + rt * 16 + hi * 4 + j;
        if (gr < N_DST) {
#pragma unroll
          for (int ct = 0; ct < 4; ct++)
            hb[(size_t)gr * HDIM + ct * 16 + li] = __float2half(acc[rt][ct][j]);
        }
      }
  }
}

// ---------------- CSR build: counting-sort partition, zero global atomics ----------------
// Buckets: (relation, dst>>9) -> 588 buckets of 512 dst nodes; bucket order == segment order.

// 1) per-chunk histogram -> hist[bucket][block] (bucket-major)
__global__ __launch_bounds__(256) void k_hist(const int* __restrict__ dst_idx,
                                              int* __restrict__ hist) {
  __shared__ int h[NBKT];
  int tid = threadIdx.x;
  int blk = blockIdx.x;
  for (int i = tid; i < NBKT; i += 256) h[i] = 0;
  __syncthreads();
  int e0 = blk * EDGE_CHUNK;
  int e1 = min(e0 + EDGE_CHUNK, RREL * NE);
  for (int idx = e0 + tid; idx < e1; idx += 256) {
    int r = idx / NE;
    int d = dst_idx[idx];
    atomicAdd(&h[r * NBKT_REL + (d >> 9)], 1);
  }
  __syncthreads();
  for (int i = tid; i < NBKT; i += 256)
    hist[(size_t)i * NBLK_BIN + blk] = h[i];
}

// 2) per-bucket exclusive scan across blocks; bucket totals out
__global__ __launch_bounds__(256) void k_colscan(int* __restrict__ hist,
                                                 int* __restrict__ bcounts) {
  __shared__ int sm[256];
  int b = blockIdx.x;
  int tid = threadIdx.x;
  int v = (tid < NBLK_BIN) ? hist[(size_t)b * NBLK_BIN + tid] : 0;
  sm[tid] = v;
  __syncthreads();
  for (int off = 1; off < 256; off <<= 1) {
    int t = (tid >= off) ? sm[tid - off] : 0;
    __syncthreads();
    sm[tid] += t;
    __syncthreads();
  }
  if (tid < NBLK_BIN) hist[(size_t)b * NBLK_BIN + tid] = sm[tid] - v;  // exclusive
  if (tid == 255) bcounts[b] = sm[255];
}

// 3) scan 588 bucket totals -> bucket_base[589]; offsets[NSEG]=3M
__global__ __launch_bounds__(256) void k_bscan(const int* __restrict__ bcounts,
                                               int* __restrict__ bucket_base,
                                               int* __restrict__ offsets) {
  __shared__ int sm[256];
  int tid = threadIdx.x;
  int base = tid * 3;
  int c[3];
#pragma unroll
  for (int k = 0; k < 3; k++) c[k] = (base + k < NBKT) ? bcounts[base + k] : 0;
  int tsum = c[0] + c[1] + c[2];
  sm[tid] = tsum;
  __syncthreads();
  for (int off = 1; off < 256; off <<= 1) {
    int v = (tid >= off) ? sm[tid - off] : 0;
    __syncthreads();
    sm[tid] += v;
    __syncthreads();
  }
  int run = sm[tid] - tsum;
#pragma unroll
  for (int k = 0; k < 3; k++) {
    if (base + k < NBKT) bucket_base[base + k] = run;
    run += c[k];
  }
  if (tid == 255) bucket_base[NBKT] = sm[255];  // = RREL*NE
  if (tid == 0) offsets[NSEG] = RREL * NE;
}

// 4) place edges: per-block LDS cursors seeded from scanned bases; LDS atomics only.
//    Packed word (localdst<<17 | src); src < 2^17, localdst < 2^9.
__global__ __launch_bounds__(256) void k_place(const int* __restrict__ src_idx,
                                               const int* __restrict__ dst_idx,
                                               const int* __restrict__ hist,
                                               const int* __restrict__ bucket_base,
                                               unsigned* __restrict__ tmp) {
  __shared__ int cur[NBKT];
  int tid = threadIdx.x;
  int blk = blockIdx.x;
  for (int i = tid; i < NBKT; i += 256)
    cur[i] = bucket_base[i] + hist[(size_t)i * NBLK_BIN + blk];
  __syncthreads();
  int e0 = blk * EDGE_CHUNK;
  int e1 = min(e0 + EDGE_CHUNK, RREL * NE);
  for (int idx = e0 + tid; idx < e1; idx += 256) {
    int r = idx / NE;
    int d = dst_idx[idx];
    int s = src_idx[idx];
    int bucket = r * NBKT_REL + (d >> 9);
    int pos = atomicAdd(&cur[bucket], 1);
    tmp[pos] = ((unsigned)(d & 511) << 17) | (unsigned)s;
  }
}

// 5) per-bucket: LDS histogram of 512 local segments + block scan -> per-segment
//    offsets + final scatter (random writes confined to ~20 KB -> L2-combined).
__global__ __launch_bounds__(256) void k_bucket_csr(
    const int* __restrict__ bucket_base, const unsigned* __restrict__ tmp,
    int* __restrict__ src_sorted, int* __restrict__ offsets) {
  __shared__ int cnt[512];
  __shared__ int base_l[512];
  __shared__ int sm[256];
  int b = blockIdx.x;
  int r = b / NBKT_REL;
  int brel = b - r * NBKT_REL;
  int gbase = bucket_base[b];
  int gend = bucket_base[b + 1];
  int tid = threadIdx.x;
  cnt[tid] = 0;
  cnt[tid + 256] = 0;
  __syncthreads();
  for (int e = gbase + tid; e < gend; e += 256)
    atomicAdd(&cnt[tmp[e] >> 17], 1);
  __syncthreads();
  int c0 = cnt[2 * tid], c1 = cnt[2 * tid + 1];
  int tsum = c0 + c1;
  sm[tid] = tsum;
  __syncthreads();
  for (int off = 1; off < 256; off <<= 1) {
    int v = (tid >= off) ? sm[tid - off] : 0;
    __syncthreads();
    sm[tid] += v;
    __syncthreads();
  }
  int run = sm[tid] - tsum;
  base_l[2 * tid] = run;
  base_l[2 * tid + 1] = run + c0;
  __syncthreads();
  for (int s = tid; s < 512; s += 256) {
    int dst = (brel << 9) + s;
    if (dst < N_DST) offsets[r * N_DST + dst] = gbase + base_l[s];
    cnt[s] = 0;
  }
  __syncthreads();
  for (int e = gbase + tid; e < gend; e += 256) {
    unsigned w = tmp[e];
    int s = w >> 17;
    int pos = gbase + base_l[s] + atomicAdd(&cnt[s], 1);
    src_sorted[pos] = (int)(w & 0x1FFFFu);
  }
}

// ---------------- GAT aggregation: 8 lanes per (relation, dst-node) ----------------
// Shuffle-free: each 8-lane group owns one segment; lane li owns dims 8li..8li+7
// (16B of the fp16 row -> 128B group load per edge). All 8 lanes redundantly
// compute the edge weight from broadcast loads (same addr in group -> L1
// broadcast), so ssum is replicated (no reduce) and accumulators are final
// (no cross-group combine, no divergent store). 8 nodes per wave amortizes
// prologue/epilogue 8x vs the old wave-per-node scheme (~36 instr/edge -> ~7).
__global__ __launch_bounds__(256) void k_aggregate(
    const int* __restrict__ offsets, const int* __restrict__ src_sorted,
    const float* __restrict__ el, const float* __restrict__ er,
    const __half* __restrict__ h16, float* __restrict__ zbuf) {
  int gw = blockIdx.x * 32 + (threadIdx.x >> 3);
  int li = threadIdx.x & 7;  // lane-in-group: dims 8*li .. 8*li+7
  if (gw >= NSEG) return;
  int r = gw / N_DST;
  int start = offsets[gw], end = offsets[gw + 1];
  float erv = er[gw];
  const unsigned char* hs = (const unsigned char*)(h16 + (size_t)r * N_DST * HDIM);
  const float* elr = el + (size_t)r * N_DST;
  float acc[8] = {};
  float ssum = 0.f;
  int sNext = (start < end) ? src_sorted[start] : 0;  // 1-deep index prefetch
  for (int e = start; e < end; ++e) {
    int s = sNext;
    if (e + 1 < end) sNext = src_sorted[e + 1];
    float x = elr[s] + erv;                     // broadcast gather (L2-resident)
    float4 rv = *(const float4*)(hs + (unsigned)(s * 128 + li * 16));
    x = (x > 0.f) ? x : 0.01f * x;              // leaky_relu
    float a = __expf(x);
    ssum += a;
    const __half2* hp = (const __half2*)&rv;
#pragma unroll
    for (int q = 0; q < 4; q++) {
      float2 f = __half22float2(hp[q]);
      acc[2 * q] += a * f.x;
      acc[2 * q + 1] += a * f.y;
    }
  }
  float inv = (end > start) ? 1.f / ssum : 0.f;
  float zv[8];
#pragma unroll
  for (int q = 0; q < 8; q++) {
    float v = acc[q] * inv;
    zv[q] = (v > 0.f) ? v : (__expf(v) - 1.f);  // elu; empty segment -> elu(0)=0
  }
  float* zp = zbuf + (size_t)gw * HDIM + li * 8;
  *(float4*)zp = make_float4(zv[0], zv[1], zv[2], zv[3]);
  *(float4*)(zp + 4) = make_float4(zv[4], zv[5], zv[6], zv[7]);
}

// ---------------- semantic attention reduce ----------------
// jj loop NOT fully unrolled (full unroll spilled: 256 VGPR + 1.5 GB scratch traffic).
__global__ __launch_bounds__(256) void k_semantic(
    const float* __restrict__ zbuf, const float* __restrict__ W1,
    const float* __restrict__ b1, const float* __restrict__ w2,
    float* __restrict__ w_acc) {
  __shared__ float W1l[64 * 128];  // 32 KB
  __shared__ float zsh[64 * 68];   // 17.4 KB, +4 pad
  __shared__ float wsum[RREL];
  int tid = threadIdx.x;
  if (tid < RREL) wsum[tid] = 0.f;
  for (int i = tid * 4; i < 64 * 128; i += 1024)
    *(float4*)(W1l + i) = *(const float4*)(W1 + i);
  long row0 = (long)blockIdx.x * 64;
  for (int t4 = tid; t4 < 1024; t4 += 256) {
    int rl = t4 >> 4;
    int j4 = (t4 & 15) << 2;
    long row = row0 + rl;
    float4 v = make_float4(0.f, 0.f, 0.f, 0.f);
    if (row < (long)NSEG) v = *(const float4*)(zbuf + row * HDIM + j4);
    *(float4*)(zsh + rl * 68 + j4) = v;
  }
  __syncthreads();
  int tc = tid & 31;
  int tr = tid >> 5;
  float acc[8][4] = {};
#pragma unroll 1
  for (int jj = 0; jj < 64; jj += 4) {
    float4 wv[4];
#pragma unroll
    for (int j = 0; j < 4; j++) wv[j] = *(float4*)(W1l + (jj + j) * 128 + 4 * tc);
#pragma unroll
    for (int ih = 0; ih < 2; ih++) {
      float4 zv[4];
#pragma unroll
      for (int i = 0; i < 4; i++) zv[i] = *(float4*)(zsh + (8 * tr + 4 * ih + i) * 68 + jj);
#pragma unroll
      for (int i = 0; i < 4; i++) {
        const float* zp = (const float*)&zv[i];
#pragma unroll
        for (int j = 0; j < 4; j++) {
          const float* wp = (const float*)&wv[j];
          float zz = zp[j];
#pragma unroll
          for (int c = 0; c < 4; c++) acc[4 * ih + i][c] += zz * wp[c];
        }
      }
    }
  }
  float b1v[4], w2v[4];
#pragma unroll
  for (int c = 0; c < 4; c++) {
    b1v[c] = b1[4 * tc + c];
    w2v[c] = w2[4 * tc + c];
  }
#pragma unroll
  for (int i = 0; i < 8; i++) {
    long row = row0 + 8 * tr + i;
    float p = 0.f;
#pragma unroll
    for (int c = 0; c < 4; c++) {
      float x = acc[i][c] + b1v[c];
      float ex = __expf(2.f * x);
      p += (1.f - 2.f / (ex + 1.f)) * w2v[c];  // tanh
    }
#pragma unroll
    for (int o = 16; o > 0; o >>= 1) p += __shfl_xor(p, o);
    if (tc == 0 && row < (long)NSEG) {
      int r = (int)(row / N_DST);
      atomicAdd(&wsum[r], p);
    }
  }
  __syncthreads();
  if (tid < RREL) atomicAdd(&w_acc[tid], wsum[tid]);
}

// ---------------- softmax over relations + weighted combine ----------------
__global__ __launch_bounds__(256) void k_final(const float* __restrict__ zbuf,
                                               const float* __restrict__ w_acc,
                                               float* __restrict__ out) {
  int idx = blockIdx.x * 256 + threadIdx.x;
  if (idx >= N_DST * HDIM / 4) return;
  const float invN = 1.0f / N_DST;
  float w0 = w_acc[0] * invN, w1 = w_acc[1] * invN, w2v = w_acc[2] * invN;
  float m = fmaxf(w0, fmaxf(w1, w2v));
  float e0 = __expf(w0 - m), e1 = __expf(w1 - m), e2 = __expf(w2v - m);
  float inv = 1.f / (e0 + e1 + e2);
  e0 *= inv; e1 *= inv; e2 *= inv;
  size_t o = (size_t)idx * 4;
  const size_t stride = (size_t)N_DST * HDIM;
  float4 z0 = *(const float4*)(zbuf + o);
  float4 z1 = *(const float4*)(zbuf + stride + o);
  float4 z2 = *(const float4*)(zbuf + 2 * stride + o);
  float4 r;
  r.x = e0 * z0.x + e1 * z1.x + e2 * z2.x;
  r.y = e0 * z0.y + e1 * z1.y + e2 * z2.y;
  r.z = e0 * z0.z + e1 * z1.z + e2 * z2.z;
  r.w = e0 * z0.w + e1 * z1.w + e2 * z2.w;
  *(float4*)(out + o) = r;
}

extern "C" void kernel_launch(void* const* d_in, const int* in_sizes, int n_in,
                              void* d_out, int out_size, void* d_ws, size_t ws_size,
                              hipStream_t stream) {
  const float* dst_feat = (const float*)d_in[0];
  const float* neigh = (const float*)d_in[1];
  const float* Wt = (const float*)d_in[2];
  const float* bt = (const float*)d_in[3];
  const float* attn_l = (const float*)d_in[4];
  const float* attn_r = (const float*)d_in[5];
  const float* W1 = (const float*)d_in[6];
  const float* b1 = (const float*)d_in[7];
  const float* w2 = (const float*)d_in[8];
  const int* src_idx = (const int*)d_in[9];
  const int* dst_idx = (const int*)d_in[10];
  float* out = (float*)d_out;

  char* p = (char*)d_ws;
  auto alloc = [&](size_t bytes) {
    char* q = p;
    p += (bytes + 255) & ~(size_t)255;
    return (void*)q;
  };
  __half* h16 = (__half*)alloc((size_t)RREL * N_DST * HDIM * 2);
  float* el = (float*)alloc((size_t)RREL * N_DST * 4);
  float* er = (float*)alloc((size_t)RREL * N_DST * 4);
  float* zbuf = (float*)alloc((size_t)RREL * N_DST * HDIM * 4);
  float* w_acc = (float*)alloc(64);
  int* offsets = (int*)alloc(((size_t)NSEG + 1) * 4);
  int* hist = (int*)alloc((size_t)NBKT * NBLK_BIN * 4);
  int* bcounts = (int*)alloc((size_t)NBKT * 4);
  int* bucket_base = (int*)alloc((size_t)(NBKT + 1) * 4);
  unsigned* tmp = (unsigned*)alloc((size_t)RREL * NE * 4);
  int* src_sorted = (int*)alloc((size_t)RREL * NE * 4);

  hipMemsetAsync(w_acc, 0, 64, stream);

  k_gemm<<<4 * ((N_DST + 127) / 128), 256, 0, stream>>>(dst_feat, neigh, Wt, bt, attn_l, attn_r,
                                                        h16, el, er);
  k_hist<<<NBLK_BIN, 256, 0, stream>>>(dst_idx, hist);
  k_colscan<<<NBKT, 256, 0, stream>>>(hist, bcounts);
  k_bscan<<<1, 256, 0, stream>>>(bcounts, bucket_base, offsets);
  k_place<<<NBLK_BIN, 256, 0, stream>>>(src_idx, dst_idx, hist, bucket_base, tmp);
  k_bucket_csr<<<NBKT, 256, 0, stream>>>(bucket_base, tmp, src_sorted, offsets);
  k_aggregate<<<(NSEG + 31) / 32, 256, 0, stream>>>(offsets, src_sorted, el, er, h16, zbuf);
  k_semantic<<<(NSEG + 63) / 64, 256, 0, stream>>>(zbuf, W1, b1, w2, w_acc);
  k_final<<<(N_DST * HDIM / 4 + 255) / 256, 256, 0, stream>>>(zbuf, w_acc, out);
}

// Round 5
// 506.085 us; speedup vs baseline: 1.5939x; 1.0787x over previous
//
#include <hip/hip_runtime.h>
#include <hip/hip_fp16.h>

#define N_DST 100000
#define DIN 128
#define HDIM 64
#define RREL 3
#define NE 1000000

#define NBKT_REL 196              // ceil(100000/512) buckets per relation
#define NBKT (RREL * NBKT_REL)    // 588 total buckets
#define NSEG (RREL * N_DST)       // 300000 segments
#define EDGE_CHUNK 16384
#define NBLK_BIN ((RREL * NE + EDGE_CHUNK - 1) / EDGE_CHUNK)  // 184

typedef _Float16 f16x8 __attribute__((ext_vector_type(8)));
typedef float f32x4 __attribute__((ext_vector_type(4)));

// ---------------- GEMM via MFMA: h = A @ W + b  (4 matrices: dst + 3 relations) ----
// fp16 inputs (error ~5e-4, same order as the fp16 h16 store we already do),
// f32 accumulate on matrix cores. Block tile 128 rows x 64 cols, K=128 staged once.
// LDS fp16 tiles XOR-swizzled (byte ^= (row&7)<<4) so stride-256B ds_read_b128
// fragment reads are 2-way (free) instead of 16-way bank conflicts.
// Epilogue: bias add + el/er logits via 16-lane xor-reduce; fp16 h store (rel mats).
__global__ __launch_bounds__(256) void k_gemm(
    const float* __restrict__ dst_feat, const float* __restrict__ neigh,
    const float* __restrict__ Wt, const float* __restrict__ bt,
    const float* __restrict__ attn_l, const float* __restrict__ attn_r,
    __half* __restrict__ h16, float* __restrict__ el, float* __restrict__ er) {
  const int RB = (N_DST + 127) / 128;  // 782 row-blocks per matrix
  int mat = blockIdx.x / RB;
  int row0 = (blockIdx.x % RB) * 128;
  const float* A = (mat == 0) ? dst_feat : (neigh + (size_t)(mat - 1) * N_DST * DIN);
  const float* W = Wt + (size_t)mat * DIN * HDIM;  // [k=128][n=64]
  const float* b = bt + mat * HDIM;

  __shared__ __align__(16) unsigned char lds[48 * 1024];
  unsigned char* ldsA = lds;           // 128 rows x 128 k fp16 = 32 KB (swizzled)
  unsigned char* ldsW = lds + 32768;   // 64 cols x 128 k fp16 = 16 KB (swizzled)

  int tid = threadIdx.x;

  // ---- stage A: 128x128 f32 -> fp16 LDS (row-major in k, swizzled) ----
#pragma unroll
  for (int i = 0; i < 8; i++) {
    int s = tid + 256 * i;  // 0..2047
    int row = s >> 4;       // 0..127
    int kb = s & 15;        // 16B (8 fp16) block along k
    int gr = row0 + row;
    if (gr >= N_DST) gr = N_DST - 1;  // clamp (tail block)
    const float* ap = A + (size_t)gr * DIN + kb * 8;
    float4 v0 = *(const float4*)ap;
    float4 v1 = *(const float4*)(ap + 4);
    f16x8 hv;
    hv[0] = (_Float16)v0.x; hv[1] = (_Float16)v0.y;
    hv[2] = (_Float16)v0.z; hv[3] = (_Float16)v0.w;
    hv[4] = (_Float16)v1.x; hv[5] = (_Float16)v1.y;
    hv[6] = (_Float16)v1.z; hv[7] = (_Float16)v1.w;
    *(f16x8*)(ldsA + row * 256 + ((kb * 16) ^ ((row & 7) << 4))) = hv;
  }

  // ---- stage W transposed: [k][n] f32 -> [n][k] fp16 LDS (swizzled) ----
  {
    int col = tid & 63;  // wave lanes cover cols 0..63 -> coalesced 256B rows
    int kq = tid >> 6;   // 0..3 (k chunk of 32)
    const float* wp = W + (size_t)(kq * 32) * HDIM + col;
    float wr[32];
#pragma unroll
    for (int m = 0; m < 32; m++) wr[m] = wp[(size_t)m * HDIM];
#pragma unroll
    for (int m8 = 0; m8 < 4; m8++) {
      f16x8 hv;
#pragma unroll
      for (int j = 0; j < 8; j++) hv[j] = (_Float16)wr[m8 * 8 + j];
      int byt = kq * 64 + m8 * 16;  // = k*2
      *(f16x8*)(ldsW + col * 256 + (byt ^ ((col & 7) << 4))) = hv;
    }
  }
  __syncthreads();

  // ---- MFMA: wave w owns rows w*32..w*32+31 (2 M-tiles) x 64 cols (4 N-tiles) ----
  int w = tid >> 6;
  int l = tid & 63;
  int li = l & 15;   // fragment row/col within tile
  int hi = l >> 4;   // k-quarter within fragment
  f32x4 acc[2][4] = {};
#pragma unroll
  for (int ks = 0; ks < 4; ks++) {
    int kbyte = ks * 64 + hi * 16;
    f16x8 af[2], bf[4];
#pragma unroll
    for (int rt = 0; rt < 2; rt++) {
      int row = w * 32 + rt * 16 + li;
      af[rt] = *(f16x8*)(ldsA + row * 256 + (kbyte ^ ((row & 7) << 4)));
    }
#pragma unroll
    for (int ct = 0; ct < 4; ct++) {
      int col = ct * 16 + li;
      bf[ct] = *(f16x8*)(ldsW + col * 256 + (kbyte ^ ((col & 7) << 4)));
    }
#pragma unroll
    for (int rt = 0; rt < 2; rt++)
#pragma unroll
      for (int ct = 0; ct < 4; ct++)
        acc[rt][ct] = __builtin_amdgcn_mfma_f32_16x16x32_f16(af[rt], bf[ct], acc[rt][ct], 0, 0, 0);
  }

  // ---- epilogue: bias, logits, fp16 h store ----
  // C/D layout: col = ct*16 + li, row(local) = w*32 + rt*16 + hi*4 + j
  float bv[4];
#pragma unroll
  for (int ct = 0; ct < 4; ct++) bv[ct] = b[ct * 16 + li];
#pragma unroll
  for (int rt = 0; rt < 2; rt++)
#pragma unroll
    for (int ct = 0; ct < 4; ct++)
#pragma unroll
      for (int j = 0; j < 4; j++) acc[rt][ct][j] += bv[ct];

  if (mat == 0) {
    // er[r][n] = h_dst[n] . attn_r[r]
#pragma unroll
    for (int r = 0; r < RREL; r++) {
      float av[4];
#pragma unroll
      for (int ct = 0; ct < 4; ct++) av[ct] = attn_r[r * HDIM + ct * 16 + li];
#pragma unroll
      for (int rt = 0; rt < 2; rt++) {
        float p[4];
#pragma unroll
        for (int j = 0; j < 4; j++)
          p[j] = acc[rt][0][j] * av[0] + acc[rt][1][j] * av[1] +
                 acc[rt][2][j] * av[2] + acc[rt][3][j] * av[3];
#pragma unroll
        for (int o = 1; o < 16; o <<= 1)
#pragma unroll
          for (int j = 0; j < 4; j++) p[j] += __shfl_xor(p[j], o);
        if (li == 0) {
#pragma unroll
          for (int j = 0; j < 4; j++) {
            int gr = row0 + w * 32 + rt * 16 + hi * 4 + j;
            if (gr < N_DST) er[r * N_DST + gr] = p[j];
          }
        }
      }
    }
  } else {
    int r = mat - 1;
    float av[4];
#pragma unroll
    for (int ct = 0; ct < 4; ct++) av[ct] = attn_l[r * HDIM + ct * 16 + li];
#pragma unroll
    for (int rt = 0; rt < 2; rt++) {
      float p[4];
#pragma unroll
      for (int j = 0; j < 4; j++)
        p[j] = acc[rt][0][j] * av[0] + acc[rt][1][j] * av[1] +
               acc[rt][2][j] * av[2] + acc[rt][3][j] * av[3];
#pragma unroll
      for (int o = 1; o < 16; o <<= 1)
#pragma unroll
        for (int j = 0; j < 4; j++) p[j] += __shfl_xor(p[j], o);
      if (li == 0) {
#pragma unroll
        for (int j = 0; j < 4; j++) {
          int gr = row0 + w * 32 + rt * 16 + hi * 4 + j;
          if (gr < N_DST) el[r * N_DST + gr] = p[j];
        }
      }
    }
    __half* hb = h16 + (size_t)r * N_DST * HDIM;
#pragma unroll
    for (int rt = 0; rt < 2; rt++)
#pragma unroll
      for (int j = 0; j < 4; j++) {
        int gr = row0 + w * 32 + rt * 16 + hi * 4 + j;
        if (gr < N_DST) {
#pragma unroll
          for (int ct = 0; ct < 4; ct++)
            hb[(size_t)gr * HDIM + ct * 16 + li] = __float2half(acc[rt][ct][j]);
        }
      }
  }
}

// ---------------- CSR build: counting-sort partition, zero global atomics ----------------
// Buckets: (relation, dst>>9) -> 588 buckets of 512 dst nodes; bucket order == segment order.

// 1) per-chunk histogram -> hist[bucket][block] (bucket-major)
__global__ __launch_bounds__(256) void k_hist(const int* __restrict__ dst_idx,
                                              int* __restrict__ hist) {
  __shared__ int h[NBKT];
  int tid = threadIdx.x;
  int blk = blockIdx.x;
  for (int i = tid; i < NBKT; i += 256) h[i] = 0;
  __syncthreads();
  int e0 = blk * EDGE_CHUNK;
  int e1 = min(e0 + EDGE_CHUNK, RREL * NE);
  for (int idx = e0 + tid; idx < e1; idx += 256) {
    int r = idx / NE;
    int d = dst_idx[idx];
    atomicAdd(&h[r * NBKT_REL + (d >> 9)], 1);
  }
  __syncthreads();
  for (int i = tid; i < NBKT; i += 256)
    hist[(size_t)i * NBLK_BIN + blk] = h[i];
}

// 2) per-bucket exclusive scan across blocks; bucket totals out
__global__ __launch_bounds__(256) void k_colscan(int* __restrict__ hist,
                                                 int* __restrict__ bcounts) {
  __shared__ int sm[256];
  int b = blockIdx.x;
  int tid = threadIdx.x;
  int v = (tid < NBLK_BIN) ? hist[(size_t)b * NBLK_BIN + tid] : 0;
  sm[tid] = v;
  __syncthreads();
  for (int off = 1; off < 256; off <<= 1) {
    int t = (tid >= off) ? sm[tid - off] : 0;
    __syncthreads();
    sm[tid] += t;
    __syncthreads();
  }
  if (tid < NBLK_BIN) hist[(size_t)b * NBLK_BIN + tid] = sm[tid] - v;  // exclusive
  if (tid == 255) bcounts[b] = sm[255];
}

// 3) scan 588 bucket totals -> bucket_base[589]; offsets[NSEG]=3M
__global__ __launch_bounds__(256) void k_bscan(const int* __restrict__ bcounts,
                                               int* __restrict__ bucket_base,
                                               int* __restrict__ offsets) {
  __shared__ int sm[256];
  int tid = threadIdx.x;
  int base = tid * 3;
  int c[3];
#pragma unroll
  for (int k = 0; k < 3; k++) c[k] = (base + k < NBKT) ? bcounts[base + k] : 0;
  int tsum = c[0] + c[1] + c[2];
  sm[tid] = tsum;
  __syncthreads();
  for (int off = 1; off < 256; off <<= 1) {
    int v = (tid >= off) ? sm[tid - off] : 0;
    __syncthreads();
    sm[tid] += v;
    __syncthreads();
  }
  int run = sm[tid] - tsum;
#pragma unroll
  for (int k = 0; k < 3; k++) {
    if (base + k < NBKT) bucket_base[base + k] = run;
    run += c[k];
  }
  if (tid == 255) bucket_base[NBKT] = sm[255];  // = RREL*NE
  if (tid == 0) offsets[NSEG] = RREL * NE;
}

// 4) place edges: per-block LDS cursors seeded from scanned bases; LDS atomics only.
//    Packed word (localdst<<17 | src); src < 2^17, localdst < 2^9.
__global__ __launch_bounds__(256) void k_place(const int* __restrict__ src_idx,
                                               const int* __restrict__ dst_idx,
                                               const int* __restrict__ hist,
                                               const int* __restrict__ bucket_base,
                                               unsigned* __restrict__ tmp) {
  __shared__ int cur[NBKT];
  int tid = threadIdx.x;
  int blk = blockIdx.x;
  for (int i = tid; i < NBKT; i += 256)
    cur[i] = bucket_base[i] + hist[(size_t)i * NBLK_BIN + blk];
  __syncthreads();
  int e0 = blk * EDGE_CHUNK;
  int e1 = min(e0 + EDGE_CHUNK, RREL * NE);
  for (int idx = e0 + tid; idx < e1; idx += 256) {
    int r = idx / NE;
    int d = dst_idx[idx];
    int s = src_idx[idx];
    int bucket = r * NBKT_REL + (d >> 9);
    int pos = atomicAdd(&cur[bucket], 1);
    tmp[pos] = ((unsigned)(d & 511) << 17) | (unsigned)s;
  }
}

// 5) per-bucket: LDS histogram of 512 local segments + block scan -> per-segment
//    offsets + final scatter (random writes confined to ~20 KB -> L2-combined).
__global__ __launch_bounds__(256) void k_bucket_csr(
    const int* __restrict__ bucket_base, const unsigned* __restrict__ tmp,
    int* __restrict__ src_sorted, int* __restrict__ offsets) {
  __shared__ int cnt[512];
  __shared__ int base_l[512];
  __shared__ int sm[256];
  int b = blockIdx.x;
  int r = b / NBKT_REL;
  int brel = b - r * NBKT_REL;
  int gbase = bucket_base[b];
  int gend = bucket_base[b + 1];
  int tid = threadIdx.x;
  cnt[tid] = 0;
  cnt[tid + 256] = 0;
  __syncthreads();
  for (int e = gbase + tid; e < gend; e += 256)
    atomicAdd(&cnt[tmp[e] >> 17], 1);
  __syncthreads();
  int c0 = cnt[2 * tid], c1 = cnt[2 * tid + 1];
  int tsum = c0 + c1;
  sm[tid] = tsum;
  __syncthreads();
  for (int off = 1; off < 256; off <<= 1) {
    int v = (tid >= off) ? sm[tid - off] : 0;
    __syncthreads();
    sm[tid] += v;
    __syncthreads();
  }
  int run = sm[tid] - tsum;
  base_l[2 * tid] = run;
  base_l[2 * tid + 1] = run + c0;
  __syncthreads();
  for (int s = tid; s < 512; s += 256) {
    int dst = (brel << 9) + s;
    if (dst < N_DST) offsets[r * N_DST + dst] = gbase + base_l[s];
    cnt[s] = 0;
  }
  __syncthreads();
  for (int e = gbase + tid; e < gend; e += 256) {
    unsigned w = tmp[e];
    int s = w >> 17;
    int pos = gbase + base_l[s] + atomicAdd(&cnt[s], 1);
    src_sorted[pos] = (int)(w & 0x1FFFFu);
  }
}

// ---------------- GAT aggregation: 8 lanes per (relation, dst-node) ----------------
// Shuffle-free: each 8-lane group owns one segment; lane li owns dims 8li..8li+7
// (16B of the fp16 row -> 128B group load per edge). All 8 lanes redundantly
// compute the edge weight from broadcast loads (same addr in group -> L1
// broadcast), so ssum is replicated (no reduce) and accumulators are final
// (no cross-group combine, no divergent store). 8 nodes per wave amortizes
// prologue/epilogue 8x vs the old wave-per-node scheme (~36 instr/edge -> ~7).
__global__ __launch_bounds__(256) void k_aggregate(
    const int* __restrict__ offsets, const int* __restrict__ src_sorted,
    const float* __restrict__ el, const float* __restrict__ er,
    const __half* __restrict__ h16, float* __restrict__ zbuf) {
  int gw = blockIdx.x * 32 + (threadIdx.x >> 3);
  int li = threadIdx.x & 7;  // lane-in-group: dims 8*li .. 8*li+7
  if (gw >= NSEG) return;
  int r = gw / N_DST;
  int start = offsets[gw], end = offsets[gw + 1];
  float erv = er[gw];
  const unsigned char* hs = (const unsigned char*)(h16 + (size_t)r * N_DST * HDIM);
  const float* elr = el + (size_t)r * N_DST;
  float acc[8] = {};
  float ssum = 0.f;
  int sNext = (start < end) ? src_sorted[start] : 0;  // 1-deep index prefetch
  for (int e = start; e < end; ++e) {
    int s = sNext;
    if (e + 1 < end) sNext = src_sorted[e + 1];
    float x = elr[s] + erv;                     // broadcast gather (L2-resident)
    float4 rv = *(const float4*)(hs + (unsigned)(s * 128 + li * 16));
    x = (x > 0.f) ? x : 0.01f * x;              // leaky_relu
    float a = __expf(x);
    ssum += a;
    const __half2* hp = (const __half2*)&rv;
#pragma unroll
    for (int q = 0; q < 4; q++) {
      float2 f = __half22float2(hp[q]);
      acc[2 * q] += a * f.x;
      acc[2 * q + 1] += a * f.y;
    }
  }
  float inv = (end > start) ? 1.f / ssum : 0.f;
  float zv[8];
#pragma unroll
  for (int q = 0; q < 8; q++) {
    float v = acc[q] * inv;
    zv[q] = (v > 0.f) ? v : (__expf(v) - 1.f);  // elu; empty segment -> elu(0)=0
  }
  float* zp = zbuf + (size_t)gw * HDIM + li * 8;
  *(float4*)zp = make_float4(zv[0], zv[1], zv[2], zv[3]);
  *(float4*)(zp + 4) = make_float4(zv[4], zv[5], zv[6], zv[7]);
}

// ---------------- semantic attention reduce (MFMA) ----------------
// z(128 rows x 64) @ W1(64 x 128) on matrix cores, fp16 inputs / f32 accum.
// Both operands staged fp16 in XOR-swizzled LDS (byte ^= (row&7)<<4, stride 128B).
// Epilogue: x+b1 -> tanh -> *w2, xor-reduce over the 16 col-lanes, guarded
// LDS wsum atomics (128-row blocks straddle the relation boundary).
__global__ __launch_bounds__(256) void k_semantic(
    const float* __restrict__ zbuf, const float* __restrict__ W1,
    const float* __restrict__ b1, const float* __restrict__ w2,
    float* __restrict__ w_acc) {
  __shared__ __align__(16) unsigned char lds[32 * 1024];
  unsigned char* ldsZ = lds;           // 128 rows x 64 k fp16 (stride 128B, swz)
  unsigned char* ldsW = lds + 16384;   // 128 cols x 64 k fp16 (stride 128B, swz)
  __shared__ float wsum[RREL];
  int tid = threadIdx.x;
  if (tid < RREL) wsum[tid] = 0.f;
  int row0 = blockIdx.x * 128;

  // ---- stage W1: [k=64][n=128] f32 -> [col][k] fp16 (coalesced k-row reads) ----
  {
    int col = tid & 127;
    int kq = tid >> 7;  // 0..1 (k chunk of 32)
    const float* wp = W1 + (size_t)(kq * 32) * 128 + col;
    float wr[32];
#pragma unroll
    for (int m = 0; m < 32; m++) wr[m] = wp[(size_t)m * 128];
#pragma unroll
    for (int m8 = 0; m8 < 4; m8++) {
      f16x8 hv;
#pragma unroll
      for (int j = 0; j < 8; j++) hv[j] = (_Float16)wr[m8 * 8 + j];
      int byt = kq * 64 + m8 * 16;  // = k*2
      *(f16x8*)(ldsW + col * 128 + (byt ^ ((col & 7) << 4))) = hv;
    }
  }
  // ---- stage z: 128 rows x 64 f32 -> fp16 [row][k] swizzled ----
#pragma unroll
  for (int i = 0; i < 4; i++) {
    int s = tid + 256 * i;  // 0..1023
    int row = s >> 3;       // 0..127
    int kb = s & 7;         // 16B (8 fp16) chunk along k
    int gr = row0 + row;
    if (gr >= NSEG) gr = NSEG - 1;  // clamp (tail; guarded at atomicAdd)
    const float* zp = zbuf + (size_t)gr * HDIM + kb * 8;
    float4 v0 = *(const float4*)zp;
    float4 v1 = *(const float4*)(zp + 4);
    f16x8 hv;
    hv[0] = (_Float16)v0.x; hv[1] = (_Float16)v0.y;
    hv[2] = (_Float16)v0.z; hv[3] = (_Float16)v0.w;
    hv[4] = (_Float16)v1.x; hv[5] = (_Float16)v1.y;
    hv[6] = (_Float16)v1.z; hv[7] = (_Float16)v1.w;
    *(f16x8*)(ldsZ + row * 128 + ((kb * 16) ^ ((row & 7) << 4))) = hv;
  }
  __syncthreads();

  // ---- MFMA: wave w owns rows w*32..w*32+31 (2 M-tiles) x 128 cols (8 N-tiles) ----
  int w = tid >> 6;
  int l = tid & 63;
  int li = l & 15;  // col within tile
  int hi = l >> 4;  // k-quarter / row-quarter
  f32x4 acc[2][8] = {};
#pragma unroll
  for (int ks = 0; ks < 2; ks++) {
    int kbyte = ks * 64 + hi * 16;
    f16x8 af[2], bf[8];
#pragma unroll
    for (int rt = 0; rt < 2; rt++) {
      int row = w * 32 + rt * 16 + li;
      af[rt] = *(f16x8*)(ldsZ + row * 128 + (kbyte ^ ((row & 7) << 4)));
    }
#pragma unroll
    for (int ct = 0; ct < 8; ct++) {
      int col = ct * 16 + li;
      bf[ct] = *(f16x8*)(ldsW + col * 128 + (kbyte ^ ((col & 7) << 4)));
    }
#pragma unroll
    for (int rt = 0; rt < 2; rt++)
#pragma unroll
      for (int ct = 0; ct < 8; ct++)
        acc[rt][ct] = __builtin_amdgcn_mfma_f32_16x16x32_f16(af[rt], bf[ct], acc[rt][ct], 0, 0, 0);
  }

  // ---- epilogue: tanh(x+b1) . w2, reduce over cols ----
  // C/D layout: col = ct*16 + li, row(local) = w*32 + rt*16 + hi*4 + j
  float p[2][4] = {};
#pragma unroll
  for (int ct = 0; ct < 8; ct++) {
    float b1v = b1[ct * 16 + li];
    float w2v = w2[ct * 16 + li];
#pragma unroll
    for (int rt = 0; rt < 2; rt++)
#pragma unroll
      for (int j = 0; j < 4; j++) {
        float x = acc[rt][ct][j] + b1v;
        float ex = __expf(2.f * x);
        p[rt][j] += (1.f - 2.f / (ex + 1.f)) * w2v;  // tanh
      }
  }
#pragma unroll
  for (int o = 1; o < 16; o <<= 1)
#pragma unroll
    for (int rt = 0; rt < 2; rt++)
#pragma unroll
      for (int j = 0; j < 4; j++) p[rt][j] += __shfl_xor(p[rt][j], o);
  if (li == 0) {
#pragma unroll
    for (int rt = 0; rt < 2; rt++)
#pragma unroll
      for (int j = 0; j < 4; j++) {
        int row = row0 + w * 32 + rt * 16 + hi * 4 + j;
        if (row < NSEG) atomicAdd(&wsum[row / N_DST], p[rt][j]);
      }
  }
  __syncthreads();
  if (tid < RREL) atomicAdd(&w_acc[tid], wsum[tid]);
}

// ---------------- softmax over relations + weighted combine ----------------
__global__ __launch_bounds__(256) void k_final(const float* __restrict__ zbuf,
                                               const float* __restrict__ w_acc,
                                               float* __restrict__ out) {
  int idx = blockIdx.x * 256 + threadIdx.x;
  if (idx >= N_DST * HDIM / 4) return;
  const float invN = 1.0f / N_DST;
  float w0 = w_acc[0] * invN, w1 = w_acc[1] * invN, w2v = w_acc[2] * invN;
  float m = fmaxf(w0, fmaxf(w1, w2v));
  float e0 = __expf(w0 - m), e1 = __expf(w1 - m), e2 = __expf(w2v - m);
  float inv = 1.f / (e0 + e1 + e2);
  e0 *= inv; e1 *= inv; e2 *= inv;
  size_t o = (size_t)idx * 4;
  const size_t stride = (size_t)N_DST * HDIM;
  float4 z0 = *(const float4*)(zbuf + o);
  float4 z1 = *(const float4*)(zbuf + stride + o);
  float4 z2 = *(const float4*)(zbuf + 2 * stride + o);
  float4 r;
  r.x = e0 * z0.x + e1 * z1.x + e2 * z2.x;
  r.y = e0 * z0.y + e1 * z1.y + e2 * z2.y;
  r.z = e0 * z0.z + e1 * z1.z + e2 * z2.z;
  r.w = e0 * z0.w + e1 * z1.w + e2 * z2.w;
  *(float4*)(out + o) = r;
}

extern "C" void kernel_launch(void* const* d_in, const int* in_sizes, int n_in,
                              void* d_out, int out_size, void* d_ws, size_t ws_size,
                              hipStream_t stream) {
  const float* dst_feat = (const float*)d_in[0];
  const float* neigh = (const float*)d_in[1];
  const float* Wt = (const float*)d_in[2];
  const float* bt = (const float*)d_in[3];
  const float* attn_l = (const float*)d_in[4];
  const float* attn_r = (const float*)d_in[5];
  const float* W1 = (const float*)d_in[6];
  const float* b1 = (const float*)d_in[7];
  const float* w2 = (const float*)d_in[8];
  const int* src_idx = (const int*)d_in[9];
  const int* dst_idx = (const int*)d_in[10];
  float* out = (float*)d_out;

  char* p = (char*)d_ws;
  auto alloc = [&](size_t bytes) {
    char* q = p;
    p += (bytes + 255) & ~(size_t)255;
    return (void*)q;
  };
  __half* h16 = (__half*)alloc((size_t)RREL * N_DST * HDIM * 2);
  float* el = (float*)alloc((size_t)RREL * N_DST * 4);
  float* er = (float*)alloc((size_t)RREL * N_DST * 4);
  float* zbuf = (float*)alloc((size_t)RREL * N_DST * HDIM * 4);
  float* w_acc = (float*)alloc(64);
  int* offsets = (int*)alloc(((size_t)NSEG + 1) * 4);
  int* hist = (int*)alloc((size_t)NBKT * NBLK_BIN * 4);
  int* bcounts = (int*)alloc((size_t)NBKT * 4);
  int* bucket_base = (int*)alloc((size_t)(NBKT + 1) * 4);
  unsigned* tmp = (unsigned*)alloc((size_t)RREL * NE * 4);
  int* src_sorted = (int*)alloc((size_t)RREL * NE * 4);

  hipMemsetAsync(w_acc, 0, 64, stream);

  k_gemm<<<4 * ((N_DST + 127) / 128), 256, 0, stream>>>(dst_feat, neigh, Wt, bt, attn_l, attn_r,
                                                        h16, el, er);
  k_hist<<<NBLK_BIN, 256, 0, stream>>>(dst_idx, hist);
  k_colscan<<<NBKT, 256, 0, stream>>>(hist, bcounts);
  k_bscan<<<1, 256, 0, stream>>>(bcounts, bucket_base, offsets);
  k_place<<<NBLK_BIN, 256, 0, stream>>>(src_idx, dst_idx, hist, bucket_base, tmp);
  k_bucket_csr<<<NBKT, 256, 0, stream>>>(bucket_base, tmp, src_sorted, offsets);
  k_aggregate<<<(NSEG + 31) / 32, 256, 0, stream>>>(offsets, src_sorted, el, er, h16, zbuf);
  k_semantic<<<(NSEG + 127) / 128, 256, 0, stream>>>(zbuf, W1, b1, w2, w_acc);
  k_final<<<(N_DST * HDIM / 4 + 255) / 256, 256, 0, stream>>>(zbuf, w_acc, out);
}